// Round 8
// baseline (543.398 us; speedup 1.0000x reference)
//
#include <hip/hip_runtime.h>
#include <hip/hip_bf16.h>
#include <math.h>

#define T_   4096
#define B_   4
#define C_   256
#define C3_  768
#define H_   1024
#define E_   4
#define M_   (B_*T_)      // 16384 rows
#define NCH_ 64
#define CHL_ (T_/NCH_)    // 64
#define KH_  4096         // E*H

typedef __attribute__((ext_vector_type(8))) short short8;
typedef __attribute__((ext_vector_type(4))) float floatx4;
typedef __attribute__((ext_vector_type(2))) long long2v;

__device__ __forceinline__ float b2f(unsigned short u) {
  union { unsigned int i; float f; } x; x.i = ((unsigned int)u) << 16; return x.f;
}
__device__ __forceinline__ unsigned short f2b(float f) {
  __hip_bfloat16 h = __float2bfloat16(f);
  return *reinterpret_cast<unsigned short*>(&h);
}
__device__ __forceinline__ void unpack8(uint4 a, float* f) {
  unsigned int w[4] = {a.x, a.y, a.z, a.w};
  #pragma unroll
  for (int i = 0; i < 4; i++) {
    union { unsigned int u; float g; } lo, hi;
    lo.u = w[i] << 16; hi.u = w[i] & 0xffff0000u;
    f[2*i] = lo.g; f[2*i+1] = hi.g;
  }
}
__device__ __forceinline__ void gl_lds16(const void* g, void* l) {
  __builtin_amdgcn_global_load_lds(
      (const __attribute__((address_space(1))) void*)g,
      (__attribute__((address_space(3))) void*)l, 16, 0, 0);
}
// sigmoid GELU: x*sigma(1.702x). |err|<=~0.01 on hid; attenuated by zero-mean w2 down-sum.
// Numerics verified on HW: passed with absmax 0.03125 using this form.
__device__ __forceinline__ float gelu_s(float v) {
  float e = __expf(-1.702f * v);
  return v * __builtin_amdgcn_rcpf(1.0f + e);
}
// pack 4 floats -> 4 fp8 e4m3 (OCP) in one uint
__device__ __forceinline__ unsigned int pk_fp8x4(float a, float b, float c, float d) {
  unsigned int v = 0;
  v = __builtin_amdgcn_cvt_pk_fp8_f32(a, b, v, false);
  v = __builtin_amdgcn_cvt_pk_fp8_f32(c, d, v, true);
  return v;
}
__device__ __forceinline__ unsigned char f2fp8(float v) {
  return (unsigned char)(__builtin_amdgcn_cvt_pk_fp8_f32(v, v, 0, false) & 0xff);
}
__device__ __forceinline__ float sel4(float4 v, int e) {
  float r = v.x;
  r = (e == 1) ? v.y : r;
  r = (e == 2) ? v.z : r;
  r = (e == 3) ? v.w : r;
  return r;
}

// ---------------- transpose + fp32->bf16: src[K,N](+z*K*N) -> dst[+z*zStr][n*dstLd + k] ----
__global__ __launch_bounds__(256) void transpose_cvt(
    const float* __restrict__ src, unsigned short* __restrict__ dst, int K, int N,
    int dstLd, size_t dstZStride) {
  __shared__ float tile[32][33];
  src += (size_t)blockIdx.z * K * N;
  dst += (size_t)blockIdx.z * dstZStride;
  int n0 = blockIdx.x * 32, k0 = blockIdx.y * 32;
  int tx = threadIdx.x, ty = threadIdx.y;   // blockDim (32,8)
  #pragma unroll
  for (int i = 0; i < 32; i += 8)
    tile[ty + i][tx] = src[(size_t)(k0 + ty + i) * N + n0 + tx];
  __syncthreads();
  #pragma unroll
  for (int i = 0; i < 32; i += 8)
    dst[(size_t)(n0 + ty + i) * dstLd + k0 + tx] = f2b(tile[tx][ty + i]);
}

// ---------------- w2 -> fp8 register layout: one byte per thread -----------------------
// w2r[((chunk*4 + cg)*4 + i)*1024 + lane*16 + kh*8 + b] = fp8(256 * w2[e][hL][c])
//   e = chunk>>4, hL = (chunk&15)*64 + kh*32 + (lane>>4)*8 + b, c = cg*64 + i*16 + (lane&15)
// Down-wave then loads its MFMA A-operands as ONE coalesced dwordx4 per (i):
//   16B = [kk=0: 8 fp8 k-values][kk=1: 8 fp8], per lane. Values/order identical to the
//   old LDS path (bit-identical numerics).
__global__ __launch_bounds__(256) void prep_w2r(
    const float* __restrict__ src, unsigned char* __restrict__ dst) {
  int flat = blockIdx.x * 256 + threadIdx.x;     // 0 .. 1M
  int b    = flat & 7;
  int kh   = (flat >> 3) & 1;
  int lane = (flat >> 4) & 63;
  int i    = (flat >> 10) & 3;
  int cg   = (flat >> 12) & 3;
  int chunk= (flat >> 14) & 63;
  int quad = lane >> 4, lm = lane & 15;
  int e    = chunk >> 4;
  int hL   = (chunk & 15) * 64 + kh * 32 + quad * 8 + b;
  int c    = cg * 64 + i * 16 + lm;
  dst[flat] = f2fp8(src[((size_t)e * H_ + hL) * C_ + c] * 256.0f);
}

// ---------------- LayerNorm 1 ----------------
__global__ __launch_bounds__(256) void ln1_kernel(
    const float* __restrict__ x, const float* __restrict__ g,
    const float* __restrict__ b, unsigned short* __restrict__ h) {
  __shared__ float red[4];
  int row = blockIdx.x, tid = threadIdx.x;
  float v = x[(size_t)row * C_ + tid];
  float s = v;
  #pragma unroll
  for (int o = 32; o; o >>= 1) s += __shfl_xor(s, o);
  if ((tid & 63) == 0) red[tid >> 6] = s;
  __syncthreads();
  float mean = (red[0] + red[1] + red[2] + red[3]) * (1.0f / C_);
  __syncthreads();
  float d = v - mean;
  float q = d * d;
  #pragma unroll
  for (int o = 32; o; o >>= 1) q += __shfl_xor(q, o);
  if ((tid & 63) == 0) red[tid >> 6] = q;
  __syncthreads();
  float var = (red[0] + red[1] + red[2] + red[3]) * (1.0f / C_);
  h[(size_t)row * C_ + tid] = f2b(d * rsqrtf(var + 1e-5f) * g[tid] + b[tid]);
}

// ---------------- LayerNorm 2 + gating softmax (h2 bf16) ----------------
__global__ __launch_bounds__(256) void ln2_gates_kernel(
    const float* __restrict__ x1, const float* __restrict__ g,
    const float* __restrict__ b, const float* __restrict__ gw,
    const float* __restrict__ gb, unsigned short* __restrict__ h2,
    float* __restrict__ gates) {
  __shared__ float red[4];
  __shared__ float redg[4][4];
  int row = blockIdx.x, tid = threadIdx.x;
  float v = x1[(size_t)row * C_ + tid];
  float s = v;
  #pragma unroll
  for (int o = 32; o; o >>= 1) s += __shfl_xor(s, o);
  if ((tid & 63) == 0) red[tid >> 6] = s;
  __syncthreads();
  float mean = (red[0] + red[1] + red[2] + red[3]) * (1.0f / C_);
  __syncthreads();
  float d = v - mean;
  float q = d * d;
  #pragma unroll
  for (int o = 32; o; o >>= 1) q += __shfl_xor(q, o);
  if ((tid & 63) == 0) red[tid >> 6] = q;
  __syncthreads();
  float var = (red[0] + red[1] + red[2] + red[3]) * (1.0f / C_);
  float hv = d * rsqrtf(var + 1e-5f) * g[tid] + b[tid];
  h2[(size_t)row * C_ + tid] = f2b(hv);
  float p0 = hv * gw[tid * 4 + 0];
  float p1 = hv * gw[tid * 4 + 1];
  float p2 = hv * gw[tid * 4 + 2];
  float p3 = hv * gw[tid * 4 + 3];
  #pragma unroll
  for (int o = 32; o; o >>= 1) {
    p0 += __shfl_xor(p0, o); p1 += __shfl_xor(p1, o);
    p2 += __shfl_xor(p2, o); p3 += __shfl_xor(p3, o);
  }
  if ((tid & 63) == 0) {
    int w = tid >> 6;
    redg[w][0] = p0; redg[w][1] = p1; redg[w][2] = p2; redg[w][3] = p3;
  }
  __syncthreads();
  if (tid == 0) {
    float t4[4];
    #pragma unroll
    for (int e = 0; e < 4; e++)
      t4[e] = redg[0][e] + redg[1][e] + redg[2][e] + redg[3][e] + gb[e];
    float m = fmaxf(fmaxf(t4[0], t4[1]), fmaxf(t4[2], t4[3]));
    float zs = 0.f;
    #pragma unroll
    for (int e = 0; e < 4; e++) { t4[e] = __expf(t4[e] - m); zs += t4[e]; }
    float inv = 1.0f / zs;
    #pragma unroll
    for (int e = 0; e < 4; e++) gates[(size_t)row * 4 + e] = t4[e] * inv;
  }
}

// ---------------- chunked prefix scan of v ----------------
__global__ __launch_bounds__(256) void scan1_kernel(const unsigned short* __restrict__ qkv,
                                                    float* __restrict__ S) {
  int b = blockIdx.x >> 6, ch = blockIdx.x & 63, c = threadIdx.x;
  float s = 0.f;
  size_t base = ((size_t)b * T_ + (size_t)ch * CHL_) * C3_ + 512 + c;
  for (int t = 0; t < CHL_; t++) s += b2f(qkv[base + (size_t)t * C3_]);
  S[((size_t)b * NCH_ + ch) * C_ + c] = s;
}
__global__ __launch_bounds__(256) void scan2_kernel(float* __restrict__ S) {
  int b = blockIdx.x, c = threadIdx.x;
  float run = 0.f;
  for (int ch = 0; ch < NCH_; ch++) {
    size_t i = ((size_t)b * NCH_ + ch) * C_ + c;
    float t = S[i]; S[i] = run; run += t;
  }
}
__global__ __launch_bounds__(256) void scan3_kernel(const unsigned short* __restrict__ qkv,
                                                    const float* __restrict__ S,
                                                    unsigned short* __restrict__ Pb) {
  int b = blockIdx.x >> 6, ch = blockIdx.x & 63, c = threadIdx.x;
  float run = S[((size_t)b * NCH_ + ch) * C_ + c];
  size_t row0 = (size_t)b * T_ + (size_t)ch * CHL_;
  for (int t = 0; t < CHL_; t++) {
    run += b2f(qkv[(row0 + t) * C3_ + 512 + c]);
    Pb[(row0 + t) * C_ + c] = f2b(run);
  }
}

// ---------------- windowed attention: 16-lane group per window position ----------------
__global__ __launch_bounds__(256) void attn_kernel(
    const unsigned short* __restrict__ qkv, const unsigned short* __restrict__ Pb,
    const float* __restrict__ gate, unsigned short* __restrict__ aout) {
  int wave = threadIdx.x >> 6, lane = threadIdx.x & 63;
  int r = blockIdx.x * 4 + wave;
  int t = r & (T_ - 1);
  int g = lane >> 4, u = lane & 15;
  const unsigned short* qp = qkv + (size_t)r * C3_ + (u << 4);
  float qv[16];
  unpack8(*(const uint4*)qp, qv);
  unpack8(*(const uint4*)(qp + 8), qv + 8);
  float sc[5];
  #pragma unroll
  for (int rnd = 0; rnd < 5; rnd++) {
    int j = rnd * 4 + g;
    int jj = t - 16 + j;
    bool valid = (j <= 16) && (jj >= 0);
    float d = 0.f;
    if (valid) {
      const unsigned short* kp = qkv + (size_t)(r - 16 + j) * C3_ + 256 + (u << 4);
      float kv[16];
      unpack8(*(const uint4*)kp, kv);
      unpack8(*(const uint4*)(kp + 8), kv + 8);
      #pragma unroll
      for (int c = 0; c < 16; c++) d += qv[c] * kv[c];
    }
    d += __shfl_xor(d, 1); d += __shfl_xor(d, 2);
    d += __shfl_xor(d, 4); d += __shfl_xor(d, 8);
    sc[rnd] = valid ? d * 0.0625f : -1e30f;
  }
  float m = fmaxf(fmaxf(fmaxf(sc[0], sc[1]), fmaxf(sc[2], sc[3])), sc[4]);
  m = fmaxf(m, __shfl_xor(m, 16));
  m = fmaxf(m, __shfl_xor(m, 32));
  if (t > 16) m = fmaxf(m, 0.0f);
  float ev[5], Zp = 0.f;
  #pragma unroll
  for (int rnd = 0; rnd < 5; rnd++) {
    ev[rnd] = (sc[rnd] > -1e29f) ? __expf(sc[rnd] - m) : 0.f;
    Zp += ev[rnd];
  }
  Zp += __shfl_xor(Zp, 16);
  Zp += __shfl_xor(Zp, 32);
  float e0v = 0.f;
  if (t > 16) { e0v = __expf(-m); Zp += e0v * (float)(t - 16); }
  float vp[16];
  #pragma unroll
  for (int c = 0; c < 16; c++) vp[c] = 0.f;
  #pragma unroll
  for (int rnd = 0; rnd < 5; rnd++) {
    if (ev[rnd] != 0.f) {
      int j = rnd * 4 + g;
      const unsigned short* vpp = qkv + (size_t)(r - 16 + j) * C3_ + 512 + (u << 4);
      float vv[16];
      unpack8(*(const uint4*)vpp, vv);
      unpack8(*(const uint4*)(vpp + 8), vv + 8);
      #pragma unroll
      for (int c = 0; c < 16; c++) vp[c] += ev[rnd] * vv[c];
    }
  }
  #pragma unroll
  for (int c = 0; c < 16; c++) {
    vp[c] += __shfl_xor(vp[c], 16);
    vp[c] += __shfl_xor(vp[c], 32);
  }
  if (g == 0) {
    if (t > 16) {
      const unsigned short* pp = Pb + (size_t)(r - 17) * C_ + (u << 4);
      float pv[16];
      unpack8(*(const uint4*)pp, pv);
      unpack8(*(const uint4*)(pp + 8), pv + 8);
      #pragma unroll
      for (int c = 0; c < 16; c++) vp[c] += e0v * pv[c];
    }
    float inv = 1.0f / Zp;
    const float* gp = gate + (u << 4);
    unsigned int ow[8];
    #pragma unroll
    for (int i = 0; i < 8; i++) {
      unsigned short lo = f2b(vp[2*i] * inv * gp[2*i]);
      unsigned short hi = f2b(vp[2*i+1] * inv * gp[2*i+1]);
      ow[i] = (unsigned int)lo | ((unsigned int)hi << 16);
    }
    uint4 s0 = {ow[0], ow[1], ow[2], ow[3]};
    uint4 s1 = {ow[4], ow[5], ow[6], ow[7]};
    *(uint4*)(aout + (size_t)r * C_ + (u << 4)) = s0;
    *(uint4*)(aout + (size_t)r * C_ + (u << 4) + 8) = s1;
  }
}

// ---------------- 128x128 MFMA GEMM, operand-swapped, swizzled staging ------------------
// EPI 0: outb = bf16(acc + bias)                              (qkv)
// EPI 1: x1 = acc + bias + resid                              (proj)
template<int EPI>
__global__ __launch_bounds__(256) void gemm128(
    const unsigned short* __restrict__ A, const unsigned short* __restrict__ Bt,
    const float* __restrict__ bias, int K, int ldOut,
    const float* __restrict__ resid, float* __restrict__ outf,
    unsigned short* __restrict__ outb) {
  __shared__ __align__(16) unsigned short As[128 * 64];
  __shared__ __align__(16) unsigned short Bs[128 * 64];
  const int tid = threadIdx.x;
  const int wave = tid >> 6, lane = tid & 63;
  const int mBlk = blockIdx.x * 128, nBlk = blockIdx.y * 128;
  const int wm = (wave >> 1) * 64, wn = (wave & 1) * 64;
  const int lm = lane & 15, lk = (lane >> 4) * 8;
  floatx4 acc[4][4];
  #pragma unroll
  for (int i = 0; i < 4; i++)
    #pragma unroll
    for (int j = 0; j < 4; j++) acc[i][j] = (floatx4){0.f, 0.f, 0.f, 0.f};

  for (int kt = 0; kt < K; kt += 64) {
    __syncthreads();
    #pragma unroll
    for (int i = 0; i < 4; i++) {
      int seg = i * 256 + tid;          // 16B segment index
      int row = seg >> 3, g = seg & 7;
      int gc = (g ^ (row & 7)) << 3;    // XOR-swizzle the GLOBAL column (LDS stays linear)
      gl_lds16(A + (size_t)(mBlk + row) * K + kt + gc, &As[seg * 8]);
      gl_lds16(Bt + (size_t)(nBlk + row) * K + kt + gc, &Bs[seg * 8]);
    }
    __syncthreads();
    #pragma unroll
    for (int kk = 0; kk < 64; kk += 32) {
      short8 mf[4], nf[4];
      #pragma unroll
      for (int j = 0; j < 4; j++) {
        int row = wm + j * 16 + lm;
        mf[j] = *(const short8*)&As[row * 64 + ((((kk + lk) >> 3) ^ (row & 7)) << 3)];
      }
      #pragma unroll
      for (int i = 0; i < 4; i++) {
        int row = wn + i * 16 + lm;
        nf[i] = *(const short8*)&Bs[row * 64 + ((((kk + lk) >> 3) ^ (row & 7)) << 3)];
      }
      #pragma unroll
      for (int i = 0; i < 4; i++)
        #pragma unroll
        for (int j = 0; j < 4; j++)
          acc[i][j] = __builtin_amdgcn_mfma_f32_16x16x32_bf16(nf[i], mf[j], acc[i][j], 0, 0, 0);
    }
  }
  const int lc = lane & 15, quad = lane >> 4, q4 = quad * 4;
  #pragma unroll
  for (int i = 0; i < 4; i++) {
    int n0 = nBlk + wn + i * 16 + q4;
    float4 bs = *(const float4*)&bias[n0];
    #pragma unroll
    for (int j = 0; j < 4; j++) {
      int m = mBlk + wm + j * 16 + lc;
      float v0 = acc[i][j][0] + bs.x, v1 = acc[i][j][1] + bs.y;
      float v2 = acc[i][j][2] + bs.z, v3 = acc[i][j][3] + bs.w;
      if (EPI == 0) {
        ushort4 o = {f2b(v0), f2b(v1), f2b(v2), f2b(v3)};
        *(ushort4*)&outb[(size_t)m * ldOut + n0] = o;
      } else {
        size_t idx = (size_t)m * ldOut + n0;
        float4 r = *(const float4*)&resid[idx];
        float4 o = {v0 + r.x, v1 + r.y, v2 + r.z, v3 + r.w};
        *(float4*)&outf[idx] = o;
      }
    }
  }
}

// ---------------- fused MoE, split-hid, 2 blocks/CU ------------------------------------
// Grid 512: block pair (p, p+256) handles the same 64 M-rows; half = blockIdx>>8 selects
// chunks [half*32, half*32+32).  512 threads: waves 0-3 up (h2@w1+gelu+fp8->Hs),
// waves 4-7 down (Hs@w2->dacc).  W2 lives in a single 16-VGPR register buffer loaded
// directly from the reg-layout w2r table (coalesced dwordx4; consumed next iter; WAR
// safe: loads issue after the MFMAs that read the old value).  LDS = W1s dbuf 64K +
// Hs dbuf 8K = 72 KB -> 2 blocks/CU -> 4 waves/SIMD (latency hiding across independent
// blocks).  Single-barrier schedule (R7-verified).  Down waves write raw partial sums
// to dpart; moe_reduce combines pair + x1 + g.b2.
__global__ __launch_bounds__(512, 4) void moe_fused(
    const unsigned short* __restrict__ h2,   // [M,256] bf16
    const unsigned short* __restrict__ w1t,  // [4096,256] bf16
    const float* __restrict__ b1,            // [4096] flat
    const unsigned char* __restrict__ w2r,   // [64][4][4][64][16] fp8 reg layout (x256)
    const float* __restrict__ gates,         // [M,4]
    float* __restrict__ dpart) {             // [512][64][256] raw partial sums
  __shared__ __align__(16) unsigned short W1s[2][64 * 256];    // 64 KB
  __shared__ __align__(16) unsigned char  Hs[2][64 * 64];      // 8 KB
  const int tid = threadIdx.x;
  const int wave = tid >> 6, lane = tid & 63;
  const int lm = lane & 15, quad = lane >> 4;
  const int half = blockIdx.x >> 8;
  const int mb = (blockIdx.x & 255) * 64;
  const int g0 = half * 32;
  const bool isUp = wave < 4;
  const int uw = wave & 3;
  const int wmu = (uw >> 1) * 32;     // up-tile m offset
  const int whu = (uw & 1) * 32;      // up-tile h offset
  const int wc  = uw * 64;            // down-tile c offset

  // stage W1 chunk g into buffer buf: 4 gl_lds/wave
  auto stageW1 = [&](int g, int buf) {
    const unsigned short* ws = w1t + (size_t)g * 64 * C_;
    #pragma unroll
    for (int t = 0; t < 4; t++) {
      int seg = t * 512 + tid;
      int row = seg >> 5, gg = seg & 31;
      int gp = (gg & 24) | ((gg & 7) ^ (row & 7));
      gl_lds16(ws + (size_t)row * C_ + gp * 8, &W1s[buf][seg * 8]);
    }
  };

  stageW1(g0, 0);

  // A-fragments -> registers (up waves): h2 rows [mb+wmu, +32), reused all 32 chunks
  short8 af[8][2];
  float4 ga[2];
  if (isUp) {
    #pragma unroll
    for (int kk = 0; kk < 8; kk++) {
      int kc = kk * 4 + quad;
      #pragma unroll
      for (int j = 0; j < 2; j++) {
        int row = mb + wmu + j * 16 + lm;
        af[kk][j] = *(const short8*)(h2 + (size_t)row * C_ + kc * 8);
      }
    }
    #pragma unroll
    for (int j = 0; j < 2; j++)
      ga[j] = *(const float4*)(gates + (size_t)(mb + wmu + j * 16 + lm) * 4);
  }

  long2v w2reg[4];      // down waves: W2 fragments for the chunk consumed NEXT iter
  floatx4 dacc[4][4];   // [i = c-frag][j = m-frag], down waves only
  #pragma unroll
  for (int i = 0; i < 4; i++)
    #pragma unroll
    for (int j = 0; j < 4; j++) dacc[i][j] = (floatx4){0.f, 0.f, 0.f, 0.f};

  // prologue: own chunk-g0 stage (and af/ga loads) landed before first barrier
  asm volatile("s_waitcnt vmcnt(0)" ::: "memory");

  for (int c = 0; c < 32; c++) {
    const int wb = c & 1;
    const int g = g0 + c;
    // single barrier: everyone's prev-iter stages landed (own vmcnt(0) before arrival)
    // and everyone finished compute(c-1) -> restage + read both safe
    __builtin_amdgcn_s_barrier();
    __builtin_amdgcn_sched_barrier(0);
    stageW1((g + 1) & 63, wb ^ 1);     // W1 for chunk g+1 (wrap harmless)

    if (isUp) {
      // ---- up-GEMM chunk g: uacc = h2[32m] x w1[32h], K=256
      floatx4 uacc[2][2];
      #pragma unroll
      for (int i = 0; i < 2; i++)
        #pragma unroll
        for (int j = 0; j < 2; j++) uacc[i][j] = (floatx4){0.f, 0.f, 0.f, 0.f};
      __builtin_amdgcn_s_setprio(1);
      #pragma unroll
      for (int kk = 0; kk < 8; kk++) {
        int kc = kk * 4 + quad;
        short8 nf[2];
        #pragma unroll
        for (int i = 0; i < 2; i++) {
          int row = whu + i * 16 + lm;
          nf[i] = *(const short8*)&W1s[wb][row * 256 + ((kc ^ (row & 7)) << 3)];
        }
        #pragma unroll
        for (int i = 0; i < 2; i++)
          #pragma unroll
          for (int j = 0; j < 2; j++)
            uacc[i][j] = __builtin_amdgcn_mfma_f32_16x16x32_bf16(nf[i], af[kk][j], uacc[i][j], 0, 0, 0);
      }
      __builtin_amdgcn_s_setprio(0);
      // ---- gelu + gate + fp8 -> Hs[wb], XOR-swizzled 8B granules (b1 read direct, L2-hot)
      int e = g >> 4;
      float gs0 = 64.0f * sel4(ga[0], e);
      float gs1 = 64.0f * sel4(ga[1], e);
      #pragma unroll
      for (int i = 0; i < 2; i++) {
        float4 bb = *(const float4*)&b1[(size_t)g * 64 + whu + i * 16 + quad * 4];
        #pragma unroll
        for (int j = 0; j < 2; j++) {
          float gs = j ? gs1 : gs0;
          unsigned int w = pk_fp8x4(gs * gelu_s(uacc[i][j][0] + bb.x),
                                    gs * gelu_s(uacc[i][j][1] + bb.y),
                                    gs * gelu_s(uacc[i][j][2] + bb.z),
                                    gs * gelu_s(uacc[i][j][3] + bb.w));
          int m = wmu + j * 16 + lm;
          int hh = whu + i * 16 + quad * 4;
          *(unsigned int*)&Hs[wb][m * 64 + ((((hh >> 3) ^ (m & 7)) << 3) | (hh & 7))] = w;
        }
      }
      asm volatile("s_waitcnt lgkmcnt(0)" ::: "memory");   // Hs writes landed before barrier
    } else {
      if (c > 0) {
        // ---- down-GEMM chunk g-1: dacc += hid8[64m x 64k] x w2[64c x 64k] (fp8)
        const int pb = wb ^ 1;
        __builtin_amdgcn_s_setprio(1);
        #pragma unroll
        for (int kk = 0; kk < 2; kk++) {
          long mfh[4];
          #pragma unroll
          for (int j = 0; j < 4; j++) {
            int m = j * 16 + lm;
            int g8 = quad + 4 * kk;
            mfh[j] = *(const long*)&Hs[pb][m * 64 + ((g8 ^ (m & 7)) << 3)];
          }
          #pragma unroll
          for (int i = 0; i < 4; i++)
            #pragma unroll
            for (int j = 0; j < 4; j++)
              dacc[i][j] = __builtin_amdgcn_mfma_f32_16x16x32_fp8_fp8(w2reg[i][kk], mfh[j], dacc[i][j], 0, 0, 0);
        }
        __builtin_amdgcn_s_setprio(0);
      }
      // load W2 fragments for chunk g (consumed next iter / drain).  Issued AFTER the
      // MFMAs that read the old regs (WAR via register dataflow); drained by vmcnt(0).
      const unsigned char* vs = w2r + ((size_t)(g * 4 + uw) * 4) * 1024 + lane * 16;
      #pragma unroll
      for (int i = 0; i < 4; i++)
        w2reg[i] = *(const long2v*)(vs + (size_t)i * 1024);
    }
    // own stage/reg loads landed before announcing arrival at the next barrier
    asm volatile("s_waitcnt vmcnt(0)" ::: "memory");
  }

  // ---- drain: final down step for chunk g0+31 (Hs[1], w2reg), then write partials
  __builtin_amdgcn_s_barrier();
  __builtin_amdgcn_sched_barrier(0);
  if (!isUp) {
    #pragma unroll
    for (int kk = 0; kk < 2; kk++) {
      long mfh[4];
      #pragma unroll
      for (int j = 0; j < 4; j++) {
        int m = j * 16 + lm;
        int g8 = quad + 4 * kk;
        mfh[j] = *(const long*)&Hs[1][m * 64 + ((g8 ^ (m & 7)) << 3)];
      }
      #pragma unroll
      for (int i = 0; i < 4; i++)
        #pragma unroll
        for (int j = 0; j < 4; j++)
          dacc[i][j] = __builtin_amdgcn_mfma_f32_16x16x32_fp8_fp8(w2reg[i][kk], mfh[j], dacc[i][j], 0, 0, 0);
    }
    // raw partial sums -> dpart[block][m][c]
    const int q4 = quad * 4;
    #pragma unroll
    for (int j = 0; j < 4; j++) {
      int m = j * 16 + lm;
      #pragma unroll
      for (int i = 0; i < 4; i++) {
        int n0 = wc + i * 16 + q4;
        *(floatx4*)&dpart[((size_t)blockIdx.x * 64 + m) * C_ + n0] = dacc[i][j];
      }
    }
  }
}

// ---------------- combine split-hid partials: out = (pA+pB)/2^14 + x1 + sum_e g_e*b2_e --
__global__ __launch_bounds__(256) void moe_reduce(
    const float* __restrict__ dpart, const float* __restrict__ x1,
    const float* __restrict__ gates, const float* __restrict__ b2,
    float* __restrict__ out) {
  int flat = blockIdx.x * 256 + threadIdx.x;     // 0 .. M*64
  int m = flat >> 6, c0 = (flat & 63) << 2;
  int pb = m >> 6, ml = m & 63;
  const float sc = 1.0f / 16384.0f;
  float4 a = *(const float4*)&dpart[((size_t)pb * 64 + ml) * C_ + c0];
  float4 b = *(const float4*)&dpart[(((size_t)pb + 256) * 64 + ml) * C_ + c0];
  float4 r = *(const float4*)&x1[(size_t)m * C_ + c0];
  float4 g4 = *(const float4*)&gates[(size_t)m * 4];
  float4 bA = *(const float4*)&b2[0 * C_ + c0];
  float4 bB = *(const float4*)&b2[1 * C_ + c0];
  float4 bC = *(const float4*)&b2[2 * C_ + c0];
  float4 bD = *(const float4*)&b2[3 * C_ + c0];
  float4 o;
  o.x = (a.x + b.x) * sc + r.x + g4.x*bA.x + g4.y*bB.x + g4.z*bC.x + g4.w*bD.x;
  o.y = (a.y + b.y) * sc + r.y + g4.x*bA.y + g4.y*bB.y + g4.z*bC.y + g4.w*bD.y;
  o.z = (a.z + b.z) * sc + r.z + g4.x*bA.z + g4.y*bB.z + g4.z*bC.z + g4.w*bD.z;
  o.w = (a.w + b.w) * sc + r.w + g4.x*bA.w + g4.y*bB.w + g4.z*bC.w + g4.w*bD.w;
  *(float4*)&out[(size_t)m * C_ + c0] = o;
}

extern "C" void kernel_launch(void* const* d_in, const int* in_sizes, int n_in,
                              void* d_out, int out_size, void* d_ws, size_t ws_size,
                              hipStream_t stream) {
  const float* x       = (const float*)d_in[0];
  const float* ln1_g   = (const float*)d_in[1];
  const float* ln1_b   = (const float*)d_in[2];
  const float* qkv_w   = (const float*)d_in[3];
  const float* qkv_b   = (const float*)d_in[4];
  const float* proj_w  = (const float*)d_in[5];
  const float* proj_b  = (const float*)d_in[6];
  const float* attn_g  = (const float*)d_in[7];
  const float* ln2_g   = (const float*)d_in[8];
  const float* ln2_b   = (const float*)d_in[9];
  const float* gat_w   = (const float*)d_in[10];
  const float* gat_b   = (const float*)d_in[11];
  const float* e_w1    = (const float*)d_in[12];
  const float* e_b1    = (const float*)d_in[13];
  const float* e_w2    = (const float*)d_in[14];
  const float* e_b2    = (const float*)d_in[15];
  float* out = (float*)d_out;

  char* p = (char*)d_ws;
  unsigned short* h    = (unsigned short*)p; p += (size_t)M_ * C_ * 2;      // 8 MB
  unsigned short* qkv  = (unsigned short*)p; p += (size_t)M_ * C3_ * 2;     // 24 MB
  unsigned short* Pb   = (unsigned short*)p; p += (size_t)M_ * C_ * 2;      // 8 MB
  unsigned short* aout = (unsigned short*)p; p += (size_t)M_ * C_ * 2;      // 8 MB
  float*          x1   = (float*)p;          p += (size_t)M_ * C_ * 4;      // 16 MB
  unsigned short* h2   = (unsigned short*)p; p += (size_t)M_ * C_ * 2;      // 8 MB
  float*          gts  = (float*)p;          p += (size_t)M_ * E_ * 4;      // 256 KB
  float*          S    = (float*)p;          p += (size_t)B_ * NCH_ * C_ * 4;
  unsigned short* wq   = (unsigned short*)p; p += (size_t)C3_ * C_ * 2;
  unsigned short* wp   = (unsigned short*)p; p += (size_t)C_ * C_ * 2;
  unsigned short* w1t  = (unsigned short*)p; p += (size_t)KH_ * C_ * 2;     // 2 MB [4096,256]
  unsigned char*  w2r  = (unsigned char*)p;  p += (size_t)C_ * KH_;         // 1 MB reg layout
  float*          dpart= (float*)p;          p += (size_t)512 * 64 * C_ * 4; // 32 MB

  dim3 t32x8(32, 8);
  transpose_cvt<<<dim3(C3_/32, C_/32, 1), t32x8, 0, stream>>>(qkv_w, wq, C_, C3_, C_, 0);
  transpose_cvt<<<dim3(C_/32, C_/32, 1),  t32x8, 0, stream>>>(proj_w, wp, C_, C_, C_, 0);
  // w1t[e*1024 + hrow][c]  (flat [4096, 256]) bf16
  transpose_cvt<<<dim3(H_/32, C_/32, E_), t32x8, 0, stream>>>(e_w1, w1t, C_, H_, C_, (size_t)H_ * C_);
  // w2 -> fp8 x256, register layout for direct per-wave dwordx4 loads
  prep_w2r<<<4096, 256, 0, stream>>>(e_w2, w2r);

  ln1_kernel<<<M_, 256, 0, stream>>>(x, ln1_g, ln1_b, h);
  gemm128<0><<<dim3(M_/128, C3_/128), 256, 0, stream>>>(h, wq, qkv_b, C_, C3_,
      nullptr, nullptr, qkv);
  scan1_kernel<<<B_*NCH_, 256, 0, stream>>>(qkv, S);
  scan2_kernel<<<B_, 256, 0, stream>>>(S);
  scan3_kernel<<<B_*NCH_, 256, 0, stream>>>(qkv, S, Pb);
  attn_kernel<<<M_/4, 256, 0, stream>>>(qkv, Pb, attn_g, aout);
  // x1 = x + aout @ proj_w + proj_b
  gemm128<1><<<dim3(M_/128, C_/128), 256, 0, stream>>>(aout, wp, proj_b, C_, C_,
      x, x1, nullptr);
  ln2_gates_kernel<<<M_, 256, 0, stream>>>(x1, ln2_g, ln2_b, gat_w, gat_b, h2, gts);
  // fused MoE split-hid: 512 blocks (2/CU), partial sums to dpart
  moe_fused<<<512, 512, 0, stream>>>(h2, w1t, e_b1, w2r, gts, dpart);
  // combine: out = (pA+pB)/2^14 + x1 + sum_e gate_e*b2_e
  moe_reduce<<<M_*64/256, 256, 0, stream>>>(dpart, x1, gts, e_b2, out);
}

// Round 9
// 541.655 us; speedup vs baseline: 1.0032x; 1.0032x over previous
//
#include <hip/hip_runtime.h>
#include <hip/hip_bf16.h>
#include <math.h>

#define T_   4096
#define B_   4
#define C_   256
#define C3_  768
#define H_   1024
#define E_   4
#define M_   (B_*T_)      // 16384 rows
#define NCH_ 64
#define CHL_ (T_/NCH_)    // 64
#define KH_  4096         // E*H

typedef __attribute__((ext_vector_type(8))) short short8;
typedef __attribute__((ext_vector_type(4))) float floatx4;
typedef __attribute__((ext_vector_type(2))) long long2v;

__device__ __forceinline__ float b2f(unsigned short u) {
  union { unsigned int i; float f; } x; x.i = ((unsigned int)u) << 16; return x.f;
}
__device__ __forceinline__ unsigned short f2b(float f) {
  __hip_bfloat16 h = __float2bfloat16(f);
  return *reinterpret_cast<unsigned short*>(&h);
}
__device__ __forceinline__ void unpack8(uint4 a, float* f) {
  unsigned int w[4] = {a.x, a.y, a.z, a.w};
  #pragma unroll
  for (int i = 0; i < 4; i++) {
    union { unsigned int u; float g; } lo, hi;
    lo.u = w[i] << 16; hi.u = w[i] & 0xffff0000u;
    f[2*i] = lo.g; f[2*i+1] = hi.g;
  }
}
__device__ __forceinline__ void gl_lds16(const void* g, void* l) {
  __builtin_amdgcn_global_load_lds(
      (const __attribute__((address_space(1))) void*)g,
      (__attribute__((address_space(3))) void*)l, 16, 0, 0);
}
// sigmoid GELU: x*sigma(1.702x). |err|<=~0.01 on hid; attenuated by zero-mean w2 down-sum.
// Numerics verified on HW: passed with absmax 0.03125 using this form.
__device__ __forceinline__ float gelu_s(float v) {
  float e = __expf(-1.702f * v);
  return v * __builtin_amdgcn_rcpf(1.0f + e);
}
// pack 4 floats -> 4 fp8 e4m3 (OCP) in one uint
__device__ __forceinline__ unsigned int pk_fp8x4(float a, float b, float c, float d) {
  unsigned int v = 0;
  v = __builtin_amdgcn_cvt_pk_fp8_f32(a, b, v, false);
  v = __builtin_amdgcn_cvt_pk_fp8_f32(c, d, v, true);
  return v;
}
__device__ __forceinline__ unsigned char f2fp8(float v) {
  return (unsigned char)(__builtin_amdgcn_cvt_pk_fp8_f32(v, v, 0, false) & 0xff);
}
__device__ __forceinline__ float sel4(float4 v, int e) {
  float r = v.x;
  r = (e == 1) ? v.y : r;
  r = (e == 2) ? v.z : r;
  r = (e == 3) ? v.w : r;
  return r;
}

// ---------------- transpose + fp32->bf16: src[K,N](+z*K*N) -> dst[+z*zStr][n*dstLd + k] ----
__global__ __launch_bounds__(256) void transpose_cvt(
    const float* __restrict__ src, unsigned short* __restrict__ dst, int K, int N,
    int dstLd, size_t dstZStride) {
  __shared__ float tile[32][33];
  src += (size_t)blockIdx.z * K * N;
  dst += (size_t)blockIdx.z * dstZStride;
  int n0 = blockIdx.x * 32, k0 = blockIdx.y * 32;
  int tx = threadIdx.x, ty = threadIdx.y;   // blockDim (32,8)
  #pragma unroll
  for (int i = 0; i < 32; i += 8)
    tile[ty + i][tx] = src[(size_t)(k0 + ty + i) * N + n0 + tx];
  __syncthreads();
  #pragma unroll
  for (int i = 0; i < 32; i += 8)
    dst[(size_t)(n0 + ty + i) * dstLd + k0 + tx] = f2b(tile[tx][ty + i]);
}

// ---------------- w2 -> fp8 register layout: one byte per thread -----------------------
// w2r[((chunk*4 + cg)*4 + i)*1024 + lane*16 + kh*8 + b] = fp8(256 * w2[e][hL][c])
//   e = chunk>>4, hL = (chunk&15)*64 + kh*32 + (lane>>4)*8 + b, c = cg*64 + i*16 + (lane&15)
// Down-wave loads its MFMA A-operands as ONE coalesced dwordx4 per (i):
//   16B = [kk=0: 8 fp8 k-values][kk=1: 8 fp8], per lane.  Layout/numerics HW-verified
//   (R8 passed with absmax 0.03125 using this exact prep + MFMA pairing).
__global__ __launch_bounds__(256) void prep_w2r(
    const float* __restrict__ src, unsigned char* __restrict__ dst) {
  int flat = blockIdx.x * 256 + threadIdx.x;     // 0 .. 1M
  int b    = flat & 7;
  int kh   = (flat >> 3) & 1;
  int lane = (flat >> 4) & 63;
  int i    = (flat >> 10) & 3;
  int cg   = (flat >> 12) & 3;
  int chunk= (flat >> 14) & 63;
  int quad = lane >> 4, lm = lane & 15;
  int e    = chunk >> 4;
  int hL   = (chunk & 15) * 64 + kh * 32 + quad * 8 + b;
  int c    = cg * 64 + i * 16 + lm;
  dst[flat] = f2fp8(src[((size_t)e * H_ + hL) * C_ + c] * 256.0f);
}

// ---------------- LayerNorm 1 ----------------
__global__ __launch_bounds__(256) void ln1_kernel(
    const float* __restrict__ x, const float* __restrict__ g,
    const float* __restrict__ b, unsigned short* __restrict__ h) {
  __shared__ float red[4];
  int row = blockIdx.x, tid = threadIdx.x;
  float v = x[(size_t)row * C_ + tid];
  float s = v;
  #pragma unroll
  for (int o = 32; o; o >>= 1) s += __shfl_xor(s, o);
  if ((tid & 63) == 0) red[tid >> 6] = s;
  __syncthreads();
  float mean = (red[0] + red[1] + red[2] + red[3]) * (1.0f / C_);
  __syncthreads();
  float d = v - mean;
  float q = d * d;
  #pragma unroll
  for (int o = 32; o; o >>= 1) q += __shfl_xor(q, o);
  if ((tid & 63) == 0) red[tid >> 6] = q;
  __syncthreads();
  float var = (red[0] + red[1] + red[2] + red[3]) * (1.0f / C_);
  h[(size_t)row * C_ + tid] = f2b(d * rsqrtf(var + 1e-5f) * g[tid] + b[tid]);
}

// ---------------- LayerNorm 2 + gating softmax (h2 bf16) ----------------
__global__ __launch_bounds__(256) void ln2_gates_kernel(
    const float* __restrict__ x1, const float* __restrict__ g,
    const float* __restrict__ b, const float* __restrict__ gw,
    const float* __restrict__ gb, unsigned short* __restrict__ h2,
    float* __restrict__ gates) {
  __shared__ float red[4];
  __shared__ float redg[4][4];
  int row = blockIdx.x, tid = threadIdx.x;
  float v = x1[(size_t)row * C_ + tid];
  float s = v;
  #pragma unroll
  for (int o = 32; o; o >>= 1) s += __shfl_xor(s, o);
  if ((tid & 63) == 0) red[tid >> 6] = s;
  __syncthreads();
  float mean = (red[0] + red[1] + red[2] + red[3]) * (1.0f / C_);
  __syncthreads();
  float d = v - mean;
  float q = d * d;
  #pragma unroll
  for (int o = 32; o; o >>= 1) q += __shfl_xor(q, o);
  if ((tid & 63) == 0) red[tid >> 6] = q;
  __syncthreads();
  float var = (red[0] + red[1] + red[2] + red[3]) * (1.0f / C_);
  float hv = d * rsqrtf(var + 1e-5f) * g[tid] + b[tid];
  h2[(size_t)row * C_ + tid] = f2b(hv);
  float p0 = hv * gw[tid * 4 + 0];
  float p1 = hv * gw[tid * 4 + 1];
  float p2 = hv * gw[tid * 4 + 2];
  float p3 = hv * gw[tid * 4 + 3];
  #pragma unroll
  for (int o = 32; o; o >>= 1) {
    p0 += __shfl_xor(p0, o); p1 += __shfl_xor(p1, o);
    p2 += __shfl_xor(p2, o); p3 += __shfl_xor(p3, o);
  }
  if ((tid & 63) == 0) {
    int w = tid >> 6;
    redg[w][0] = p0; redg[w][1] = p1; redg[w][2] = p2; redg[w][3] = p3;
  }
  __syncthreads();
  if (tid == 0) {
    float t4[4];
    #pragma unroll
    for (int e = 0; e < 4; e++)
      t4[e] = redg[0][e] + redg[1][e] + redg[2][e] + redg[3][e] + gb[e];
    float m = fmaxf(fmaxf(t4[0], t4[1]), fmaxf(t4[2], t4[3]));
    float zs = 0.f;
    #pragma unroll
    for (int e = 0; e < 4; e++) { t4[e] = __expf(t4[e] - m); zs += t4[e]; }
    float inv = 1.0f / zs;
    #pragma unroll
    for (int e = 0; e < 4; e++) gates[(size_t)row * 4 + e] = t4[e] * inv;
  }
}

// ---------------- chunked prefix scan of v ----------------
__global__ __launch_bounds__(256) void scan1_kernel(const unsigned short* __restrict__ qkv,
                                                    float* __restrict__ S) {
  int b = blockIdx.x >> 6, ch = blockIdx.x & 63, c = threadIdx.x;
  float s = 0.f;
  size_t base = ((size_t)b * T_ + (size_t)ch * CHL_) * C3_ + 512 + c;
  for (int t = 0; t < CHL_; t++) s += b2f(qkv[base + (size_t)t * C3_]);
  S[((size_t)b * NCH_ + ch) * C_ + c] = s;
}
__global__ __launch_bounds__(256) void scan2_kernel(float* __restrict__ S) {
  int b = blockIdx.x, c = threadIdx.x;
  float run = 0.f;
  for (int ch = 0; ch < NCH_; ch++) {
    size_t i = ((size_t)b * NCH_ + ch) * C_ + c;
    float t = S[i]; S[i] = run; run += t;
  }
}
__global__ __launch_bounds__(256) void scan3_kernel(const unsigned short* __restrict__ qkv,
                                                    const float* __restrict__ S,
                                                    unsigned short* __restrict__ Pb) {
  int b = blockIdx.x >> 6, ch = blockIdx.x & 63, c = threadIdx.x;
  float run = S[((size_t)b * NCH_ + ch) * C_ + c];
  size_t row0 = (size_t)b * T_ + (size_t)ch * CHL_;
  for (int t = 0; t < CHL_; t++) {
    run += b2f(qkv[(row0 + t) * C3_ + 512 + c]);
    Pb[(row0 + t) * C_ + c] = f2b(run);
  }
}

// ---------------- windowed attention: 16-lane group per window position ----------------
__global__ __launch_bounds__(256) void attn_kernel(
    const unsigned short* __restrict__ qkv, const unsigned short* __restrict__ Pb,
    const float* __restrict__ gate, unsigned short* __restrict__ aout) {
  int wave = threadIdx.x >> 6, lane = threadIdx.x & 63;
  int r = blockIdx.x * 4 + wave;
  int t = r & (T_ - 1);
  int g = lane >> 4, u = lane & 15;
  const unsigned short* qp = qkv + (size_t)r * C3_ + (u << 4);
  float qv[16];
  unpack8(*(const uint4*)qp, qv);
  unpack8(*(const uint4*)(qp + 8), qv + 8);
  float sc[5];
  #pragma unroll
  for (int rnd = 0; rnd < 5; rnd++) {
    int j = rnd * 4 + g;
    int jj = t - 16 + j;
    bool valid = (j <= 16) && (jj >= 0);
    float d = 0.f;
    if (valid) {
      const unsigned short* kp = qkv + (size_t)(r - 16 + j) * C3_ + 256 + (u << 4);
      float kv[16];
      unpack8(*(const uint4*)kp, kv);
      unpack8(*(const uint4*)(kp + 8), kv + 8);
      #pragma unroll
      for (int c = 0; c < 16; c++) d += qv[c] * kv[c];
    }
    d += __shfl_xor(d, 1); d += __shfl_xor(d, 2);
    d += __shfl_xor(d, 4); d += __shfl_xor(d, 8);
    sc[rnd] = valid ? d * 0.0625f : -1e30f;
  }
  float m = fmaxf(fmaxf(fmaxf(sc[0], sc[1]), fmaxf(sc[2], sc[3])), sc[4]);
  m = fmaxf(m, __shfl_xor(m, 16));
  m = fmaxf(m, __shfl_xor(m, 32));
  if (t > 16) m = fmaxf(m, 0.0f);
  float ev[5], Zp = 0.f;
  #pragma unroll
  for (int rnd = 0; rnd < 5; rnd++) {
    ev[rnd] = (sc[rnd] > -1e29f) ? __expf(sc[rnd] - m) : 0.f;
    Zp += ev[rnd];
  }
  Zp += __shfl_xor(Zp, 16);
  Zp += __shfl_xor(Zp, 32);
  float e0v = 0.f;
  if (t > 16) { e0v = __expf(-m); Zp += e0v * (float)(t - 16); }
  float vp[16];
  #pragma unroll
  for (int c = 0; c < 16; c++) vp[c] = 0.f;
  #pragma unroll
  for (int rnd = 0; rnd < 5; rnd++) {
    if (ev[rnd] != 0.f) {
      int j = rnd * 4 + g;
      const unsigned short* vpp = qkv + (size_t)(r - 16 + j) * C3_ + 512 + (u << 4);
      float vv[16];
      unpack8(*(const uint4*)vpp, vv);
      unpack8(*(const uint4*)(vpp + 8), vv + 8);
      #pragma unroll
      for (int c = 0; c < 16; c++) vp[c] += ev[rnd] * vv[c];
    }
  }
  #pragma unroll
  for (int c = 0; c < 16; c++) {
    vp[c] += __shfl_xor(vp[c], 16);
    vp[c] += __shfl_xor(vp[c], 32);
  }
  if (g == 0) {
    if (t > 16) {
      const unsigned short* pp = Pb + (size_t)(r - 17) * C_ + (u << 4);
      float pv[16];
      unpack8(*(const uint4*)pp, pv);
      unpack8(*(const uint4*)(pp + 8), pv + 8);
      #pragma unroll
      for (int c = 0; c < 16; c++) vp[c] += e0v * pv[c];
    }
    float inv = 1.0f / Zp;
    const float* gp = gate + (u << 4);
    unsigned int ow[8];
    #pragma unroll
    for (int i = 0; i < 8; i++) {
      unsigned short lo = f2b(vp[2*i] * inv * gp[2*i]);
      unsigned short hi = f2b(vp[2*i+1] * inv * gp[2*i+1]);
      ow[i] = (unsigned int)lo | ((unsigned int)hi << 16);
    }
    uint4 s0 = {ow[0], ow[1], ow[2], ow[3]};
    uint4 s1 = {ow[4], ow[5], ow[6], ow[7]};
    *(uint4*)(aout + (size_t)r * C_ + (u << 4)) = s0;
    *(uint4*)(aout + (size_t)r * C_ + (u << 4) + 8) = s1;
  }
}

// ---------------- 128x128 MFMA GEMM, operand-swapped, swizzled staging ------------------
// EPI 0: outb = bf16(acc + bias)                              (qkv)
// EPI 1: x1 = acc + bias + resid                              (proj)
template<int EPI>
__global__ __launch_bounds__(256) void gemm128(
    const unsigned short* __restrict__ A, const unsigned short* __restrict__ Bt,
    const float* __restrict__ bias, int K, int ldOut,
    const float* __restrict__ resid, float* __restrict__ outf,
    unsigned short* __restrict__ outb) {
  __shared__ __align__(16) unsigned short As[128 * 64];
  __shared__ __align__(16) unsigned short Bs[128 * 64];
  const int tid = threadIdx.x;
  const int wave = tid >> 6, lane = tid & 63;
  const int mBlk = blockIdx.x * 128, nBlk = blockIdx.y * 128;
  const int wm = (wave >> 1) * 64, wn = (wave & 1) * 64;
  const int lm = lane & 15, lk = (lane >> 4) * 8;
  floatx4 acc[4][4];
  #pragma unroll
  for (int i = 0; i < 4; i++)
    #pragma unroll
    for (int j = 0; j < 4; j++) acc[i][j] = (floatx4){0.f, 0.f, 0.f, 0.f};

  for (int kt = 0; kt < K; kt += 64) {
    __syncthreads();
    #pragma unroll
    for (int i = 0; i < 4; i++) {
      int seg = i * 256 + tid;          // 16B segment index
      int row = seg >> 3, g = seg & 7;
      int gc = (g ^ (row & 7)) << 3;    // XOR-swizzle the GLOBAL column (LDS stays linear)
      gl_lds16(A + (size_t)(mBlk + row) * K + kt + gc, &As[seg * 8]);
      gl_lds16(Bt + (size_t)(nBlk + row) * K + kt + gc, &Bs[seg * 8]);
    }
    __syncthreads();
    #pragma unroll
    for (int kk = 0; kk < 64; kk += 32) {
      short8 mf[4], nf[4];
      #pragma unroll
      for (int j = 0; j < 4; j++) {
        int row = wm + j * 16 + lm;
        mf[j] = *(const short8*)&As[row * 64 + ((((kk + lk) >> 3) ^ (row & 7)) << 3)];
      }
      #pragma unroll
      for (int i = 0; i < 4; i++) {
        int row = wn + i * 16 + lm;
        nf[i] = *(const short8*)&Bs[row * 64 + ((((kk + lk) >> 3) ^ (row & 7)) << 3)];
      }
      #pragma unroll
      for (int i = 0; i < 4; i++)
        #pragma unroll
        for (int j = 0; j < 4; j++)
          acc[i][j] = __builtin_amdgcn_mfma_f32_16x16x32_bf16(nf[i], mf[j], acc[i][j], 0, 0, 0);
    }
  }
  const int lc = lane & 15, quad = lane >> 4, q4 = quad * 4;
  #pragma unroll
  for (int i = 0; i < 4; i++) {
    int n0 = nBlk + wn + i * 16 + q4;
    float4 bs = *(const float4*)&bias[n0];
    #pragma unroll
    for (int j = 0; j < 4; j++) {
      int m = mBlk + wm + j * 16 + lc;
      float v0 = acc[i][j][0] + bs.x, v1 = acc[i][j][1] + bs.y;
      float v2 = acc[i][j][2] + bs.z, v3 = acc[i][j][3] + bs.w;
      if (EPI == 0) {
        ushort4 o = {f2b(v0), f2b(v1), f2b(v2), f2b(v3)};
        *(ushort4*)&outb[(size_t)m * ldOut + n0] = o;
      } else {
        size_t idx = (size_t)m * ldOut + n0;
        float4 r = *(const float4*)&resid[idx];
        float4 o = {v0 + r.x, v1 + r.y, v2 + r.z, v3 + r.w};
        *(float4*)&outf[idx] = o;
      }
    }
  }
}

// ---------------- fused MoE, producer/consumer wave split, register-lean ----------------
// Grid 256, 64 rows/block, 64 chunks of 64 hid.  512 threads: waves 0-3 up (each 16m x
// 64h: af[8] = 32 VGPR, half of R7's 64), waves 4-7 down (64m x 64c; W2 in a 16-VGPR
// register buffer loaded from the w2r reg-layout table -> no W2s in LDS).
// LDS = W1s dbuf 64K + Hs dbuf 8K + B1s 0.5K = 72.5 KB -> 2 blocks/CU.
// __launch_bounds__(512,4): forces total regs <=128/lane; per-wave demand now ~85-116,
// so no spill (R4/R8's failure mode was demand > 128 under this bound).
// Single-barrier schedule (R7-verified): barrier -> stage-issue -> compute -> vmcnt(0).
__global__ __launch_bounds__(512, 4) void moe_fused(
    const unsigned short* __restrict__ h2,   // [M,256] bf16
    const unsigned short* __restrict__ w1t,  // [4096,256] bf16
    const float* __restrict__ b1,            // [4096] flat
    const unsigned char* __restrict__ w2r,   // [64][4][4][64][16] fp8 reg layout (x256)
    const float* __restrict__ b2,            // [4][256]
    const float* __restrict__ gates,         // [M,4]
    const float* __restrict__ x1,            // [M,256]
    float* __restrict__ out) {
  __shared__ __align__(16) unsigned short W1s[2][64 * 256];    // 64 KB
  __shared__ __align__(16) unsigned char  Hs[2][64 * 64];      // 8 KB
  __shared__ __align__(16) float          B1s[2][64];          // 512 B
  const int tid = threadIdx.x;
  const int wave = tid >> 6, lane = tid & 63;
  const int lm = lane & 15, quad = lane >> 4;
  const int mb = blockIdx.x * 64;
  const bool isUp = wave < 4;
  const int uw = wave & 3;
  const int wmu = uw * 16;            // up-tile m offset (16 rows per wave)
  const int wc  = uw * 64;            // down-tile c offset

  // stage W1 chunk c + b1 slice into buffer buf: 5 vmem instrs/wave
  auto stageW1 = [&](int c, int buf) {
    const unsigned short* ws = w1t + (size_t)c * 64 * C_;
    #pragma unroll
    for (int t = 0; t < 4; t++) {
      int seg = t * 512 + tid;
      int row = seg >> 5, g = seg & 31;
      int gp = (g & 24) | ((g & 7) ^ (row & 7));
      gl_lds16(ws + (size_t)row * C_ + gp * 8, &W1s[buf][seg * 8]);
    }
    if (lane < 16)
      gl_lds16(b1 + (size_t)c * 64 + lane * 4, &B1s[buf][0]);
  };

  stageW1(0, 0);

  // A-fragments -> registers (up waves): h2 rows [mb+wmu, +16), reused 64 chunks.
  // af[8] = 32 VGPR (16 rows x K=256 slice per lane).
  short8 af[8];
  float4 ga;
  if (isUp) {
    int row = mb + wmu + lm;
    #pragma unroll
    for (int kk = 0; kk < 8; kk++)
      af[kk] = *(const short8*)(h2 + (size_t)row * C_ + (kk * 4 + quad) * 8);
    ga = *(const float4*)(gates + (size_t)row * 4);
  }

  long2v w2reg[4];      // down waves: W2 fragments for the chunk consumed NEXT iter
  floatx4 dacc[4][4];   // [i = c-frag][j = m-frag], down waves only
  #pragma unroll
  for (int i = 0; i < 4; i++)
    #pragma unroll
    for (int j = 0; j < 4; j++) dacc[i][j] = (floatx4){0.f, 0.f, 0.f, 0.f};

  // prologue: own chunk-0 stage (and af/ga loads) landed before first barrier
  asm volatile("s_waitcnt vmcnt(0)" ::: "memory");

  for (int c = 0; c < 64; c++) {
    const int wb = c & 1;
    // single barrier: everyone's prev-iter stages landed (own vmcnt(0) before arrival)
    // and everyone finished compute(c-1) -> restage + read both safe
    __builtin_amdgcn_s_barrier();
    __builtin_amdgcn_sched_barrier(0);
    stageW1((c + 1) & 63, wb ^ 1);     // W1/b1 for chunk c+1 (wrap harmless)

    if (isUp) {
      // ---- up-GEMM chunk c: uacc[i] = h2[16m] x w1[64h], K=256
      floatx4 uacc[4];
      #pragma unroll
      for (int i = 0; i < 4; i++) uacc[i] = (floatx4){0.f, 0.f, 0.f, 0.f};
      __builtin_amdgcn_s_setprio(1);
      #pragma unroll
      for (int kk = 0; kk < 8; kk++) {
        int kc = kk * 4 + quad;
        #pragma unroll
        for (int i = 0; i < 4; i++) {
          int row = i * 16 + lm;
          short8 nf = *(const short8*)&W1s[wb][row * 256 + ((kc ^ (row & 7)) << 3)];
          uacc[i] = __builtin_amdgcn_mfma_f32_16x16x32_bf16(nf, af[kk], uacc[i], 0, 0, 0);
        }
      }
      __builtin_amdgcn_s_setprio(0);
      // ---- gelu + gate + fp8 -> Hs[wb], XOR-swizzled 8B granules
      float gs = 64.0f * sel4(ga, c >> 4);
      int m = wmu + lm;
      #pragma unroll
      for (int i = 0; i < 4; i++) {
        float4 bb = *(const float4*)&B1s[wb][i * 16 + quad * 4];
        unsigned int w = pk_fp8x4(gs * gelu_s(uacc[i][0] + bb.x),
                                  gs * gelu_s(uacc[i][1] + bb.y),
                                  gs * gelu_s(uacc[i][2] + bb.z),
                                  gs * gelu_s(uacc[i][3] + bb.w));
        int hh = i * 16 + quad * 4;
        *(unsigned int*)&Hs[wb][m * 64 + ((((hh >> 3) ^ (m & 7)) << 3) | (hh & 7))] = w;
      }
      asm volatile("s_waitcnt lgkmcnt(0)" ::: "memory");   // Hs writes landed before barrier
    } else {
      if (c > 0) {
        // ---- down-GEMM chunk c-1: dacc += hid8[64m x 64k] x w2[64c x 64k] (fp8)
        const int pb = wb ^ 1;
        __builtin_amdgcn_s_setprio(1);
        #pragma unroll
        for (int kk = 0; kk < 2; kk++) {
          long mfh[4];
          #pragma unroll
          for (int j = 0; j < 4; j++) {
            int m = j * 16 + lm;
            int g8 = quad + 4 * kk;
            mfh[j] = *(const long*)&Hs[pb][m * 64 + ((g8 ^ (m & 7)) << 3)];
          }
          #pragma unroll
          for (int i = 0; i < 4; i++)
            #pragma unroll
            for (int j = 0; j < 4; j++)
              dacc[i][j] = __builtin_amdgcn_mfma_f32_16x16x32_fp8_fp8(w2reg[i][kk], mfh[j], dacc[i][j], 0, 0, 0);
        }
        __builtin_amdgcn_s_setprio(0);
      }
      // load W2 fragments for chunk c (consumed next iter / drain).  Issued AFTER the
      // MFMAs that read the old regs (WAR via register dataflow); drained by vmcnt(0).
      const unsigned char* vs = w2r + ((size_t)(c * 4 + uw) * 4) * 1024 + lane * 16;
      #pragma unroll
      for (int i = 0; i < 4; i++)
        w2reg[i] = *(const long2v*)(vs + (size_t)i * 1024);
    }
    // own stage/reg loads landed before announcing arrival at the next barrier
    asm volatile("s_waitcnt vmcnt(0)" ::: "memory");
  }

  // ---- drain: final down step for chunk 63 (Hs[1], w2reg), then epilogue
  __builtin_amdgcn_s_barrier();
  __builtin_amdgcn_sched_barrier(0);
  if (!isUp) {
    #pragma unroll
    for (int kk = 0; kk < 2; kk++) {
      long mfh[4];
      #pragma unroll
      for (int j = 0; j < 4; j++) {
        int m = j * 16 + lm;
        int g8 = quad + 4 * kk;
        mfh[j] = *(const long*)&Hs[1][m * 64 + ((g8 ^ (m & 7)) << 3)];
      }
      #pragma unroll
      for (int i = 0; i < 4; i++)
        #pragma unroll
        for (int j = 0; j < 4; j++)
          dacc[i][j] = __builtin_amdgcn_mfma_f32_16x16x32_fp8_fp8(w2reg[i][kk], mfh[j], dacc[i][j], 0, 0, 0);
    }
    // ---- epilogue: out = dacc/2^14 + x1 + sum_e gate_e * b2_e
    const float sc = 1.0f / 16384.0f;
    const int q4 = quad * 4;
    #pragma unroll
    for (int j = 0; j < 4; j++) {
      int m = mb + j * 16 + lm;
      float4 g4 = *(const float4*)(gates + (size_t)m * 4);
      #pragma unroll
      for (int i = 0; i < 4; i++) {
        int n0 = wc + i * 16 + q4;
        float4 bA = *(const float4*)&b2[0 * C_ + n0];
        float4 bB = *(const float4*)&b2[1 * C_ + n0];
        float4 bC = *(const float4*)&b2[2 * C_ + n0];
        float4 bD = *(const float4*)&b2[3 * C_ + n0];
        size_t idx = (size_t)m * C_ + n0;
        float4 r = *(const float4*)&x1[idx];
        float4 o;
        o.x = dacc[i][j][0]*sc + r.x + g4.x*bA.x + g4.y*bB.x + g4.z*bC.x + g4.w*bD.x;
        o.y = dacc[i][j][1]*sc + r.y + g4.x*bA.y + g4.y*bB.y + g4.z*bC.y + g4.w*bD.y;
        o.z = dacc[i][j][2]*sc + r.z + g4.x*bA.z + g4.y*bB.z + g4.z*bC.z + g4.w*bD.z;
        o.w = dacc[i][j][3]*sc + r.w + g4.x*bA.w + g4.y*bB.w + g4.z*bC.w + g4.w*bD.w;
        *(float4*)&out[idx] = o;
      }
    }
  }
}

extern "C" void kernel_launch(void* const* d_in, const int* in_sizes, int n_in,
                              void* d_out, int out_size, void* d_ws, size_t ws_size,
                              hipStream_t stream) {
  const float* x       = (const float*)d_in[0];
  const float* ln1_g   = (const float*)d_in[1];
  const float* ln1_b   = (const float*)d_in[2];
  const float* qkv_w   = (const float*)d_in[3];
  const float* qkv_b   = (const float*)d_in[4];
  const float* proj_w  = (const float*)d_in[5];
  const float* proj_b  = (const float*)d_in[6];
  const float* attn_g  = (const float*)d_in[7];
  const float* ln2_g   = (const float*)d_in[8];
  const float* ln2_b   = (const float*)d_in[9];
  const float* gat_w   = (const float*)d_in[10];
  const float* gat_b   = (const float*)d_in[11];
  const float* e_w1    = (const float*)d_in[12];
  const float* e_b1    = (const float*)d_in[13];
  const float* e_w2    = (const float*)d_in[14];
  const float* e_b2    = (const float*)d_in[15];
  float* out = (float*)d_out;

  char* p = (char*)d_ws;
  unsigned short* h    = (unsigned short*)p; p += (size_t)M_ * C_ * 2;      // 8 MB
  unsigned short* qkv  = (unsigned short*)p; p += (size_t)M_ * C3_ * 2;     // 24 MB
  unsigned short* Pb   = (unsigned short*)p; p += (size_t)M_ * C_ * 2;      // 8 MB
  unsigned short* aout = (unsigned short*)p; p += (size_t)M_ * C_ * 2;      // 8 MB
  float*          x1   = (float*)p;          p += (size_t)M_ * C_ * 4;      // 16 MB
  unsigned short* h2   = (unsigned short*)p; p += (size_t)M_ * C_ * 2;      // 8 MB
  float*          gts  = (float*)p;          p += (size_t)M_ * E_ * 4;      // 256 KB
  float*          S    = (float*)p;          p += (size_t)B_ * NCH_ * C_ * 4;
  unsigned short* wq   = (unsigned short*)p; p += (size_t)C3_ * C_ * 2;
  unsigned short* wp   = (unsigned short*)p; p += (size_t)C_ * C_ * 2;
  unsigned short* w1t  = (unsigned short*)p; p += (size_t)KH_ * C_ * 2;     // 2 MB [4096,256]
  unsigned char*  w2r  = (unsigned char*)p;  p += (size_t)C_ * KH_;         // 1 MB reg layout

  dim3 t32x8(32, 8);
  transpose_cvt<<<dim3(C3_/32, C_/32, 1), t32x8, 0, stream>>>(qkv_w, wq, C_, C3_, C_, 0);
  transpose_cvt<<<dim3(C_/32, C_/32, 1),  t32x8, 0, stream>>>(proj_w, wp, C_, C_, C_, 0);
  // w1t[e*1024 + hrow][c]  (flat [4096, 256]) bf16
  transpose_cvt<<<dim3(H_/32, C_/32, E_), t32x8, 0, stream>>>(e_w1, w1t, C_, H_, C_, (size_t)H_ * C_);
  // w2 -> fp8 x256, register layout for direct per-wave dwordx4 loads
  prep_w2r<<<4096, 256, 0, stream>>>(e_w2, w2r);

  ln1_kernel<<<M_, 256, 0, stream>>>(x, ln1_g, ln1_b, h);
  gemm128<0><<<dim3(M_/128, C3_/128), 256, 0, stream>>>(h, wq, qkv_b, C_, C3_,
      nullptr, nullptr, qkv);
  scan1_kernel<<<B_*NCH_, 256, 0, stream>>>(qkv, S);
  scan2_kernel<<<B_, 256, 0, stream>>>(S);
  scan3_kernel<<<B_*NCH_, 256, 0, stream>>>(qkv, S, Pb);
  attn_kernel<<<M_/4, 256, 0, stream>>>(qkv, Pb, attn_g, aout);
  // x1 = x + aout @ proj_w + proj_b
  gemm128<1><<<dim3(M_/128, C_/128), 256, 0, stream>>>(aout, wp, proj_b, C_, C_,
      x, x1, nullptr);
  ln2_gates_kernel<<<M_, 256, 0, stream>>>(x1, ln2_g, ln2_b, gat_w, gat_b, h2, gts);
  // fused MoE: register-lean producer/consumer, 72.5 KB LDS -> 2 blocks/CU
  moe_fused<<<M_/64, 512, 0, stream>>>(h2, w1t, e_b1, w2r, e_b2, gts, x1, out);
}

// Round 10
// 331.033 us; speedup vs baseline: 1.6415x; 1.6363x over previous
//
#include <hip/hip_runtime.h>
#include <hip/hip_bf16.h>
#include <math.h>

#define T_   4096
#define B_   4
#define C_   256
#define C3_  768
#define H_   1024
#define E_   4
#define M_   (B_*T_)      // 16384 rows
#define NCH_ 64
#define CHL_ (T_/NCH_)    // 64
#define KH_  4096         // E*H

typedef __attribute__((ext_vector_type(8))) short short8;
typedef __attribute__((ext_vector_type(4))) float floatx4;
typedef __attribute__((ext_vector_type(2))) long long2v;

__device__ __forceinline__ float b2f(unsigned short u) {
  union { unsigned int i; float f; } x; x.i = ((unsigned int)u) << 16; return x.f;
}
__device__ __forceinline__ unsigned short f2b(float f) {
  __hip_bfloat16 h = __float2bfloat16(f);
  return *reinterpret_cast<unsigned short*>(&h);
}
__device__ __forceinline__ void unpack8(uint4 a, float* f) {
  unsigned int w[4] = {a.x, a.y, a.z, a.w};
  #pragma unroll
  for (int i = 0; i < 4; i++) {
    union { unsigned int u; float g; } lo, hi;
    lo.u = w[i] << 16; hi.u = w[i] & 0xffff0000u;
    f[2*i] = lo.g; f[2*i+1] = hi.g;
  }
}
__device__ __forceinline__ void gl_lds16(const void* g, void* l) {
  __builtin_amdgcn_global_load_lds(
      (const __attribute__((address_space(1))) void*)g,
      (__attribute__((address_space(3))) void*)l, 16, 0, 0);
}
// sigmoid GELU: x*sigma(1.702x). |err|<=~0.01 on hid; attenuated by zero-mean w2 down-sum.
// Numerics verified on HW: passed with absmax 0.03125 using this form.
__device__ __forceinline__ float gelu_s(float v) {
  float e = __expf(-1.702f * v);
  return v * __builtin_amdgcn_rcpf(1.0f + e);
}
// pack 4 floats -> 4 fp8 e4m3 (OCP) in one uint
__device__ __forceinline__ unsigned int pk_fp8x4(float a, float b, float c, float d) {
  unsigned int v = 0;
  v = __builtin_amdgcn_cvt_pk_fp8_f32(a, b, v, false);
  v = __builtin_amdgcn_cvt_pk_fp8_f32(c, d, v, true);
  return v;
}
__device__ __forceinline__ unsigned char f2fp8(float v) {
  return (unsigned char)(__builtin_amdgcn_cvt_pk_fp8_f32(v, v, 0, false) & 0xff);
}
__device__ __forceinline__ float sel4(float4 v, int e) {
  float r = v.x;
  r = (e == 1) ? v.y : r;
  r = (e == 2) ? v.z : r;
  r = (e == 3) ? v.w : r;
  return r;
}

// ---------------- transpose + fp32->bf16: src[K,N](+z*K*N) -> dst[+z*zStr][n*dstLd + k] ----
__global__ __launch_bounds__(256) void transpose_cvt(
    const float* __restrict__ src, unsigned short* __restrict__ dst, int K, int N,
    int dstLd, size_t dstZStride) {
  __shared__ float tile[32][33];
  src += (size_t)blockIdx.z * K * N;
  dst += (size_t)blockIdx.z * dstZStride;
  int n0 = blockIdx.x * 32, k0 = blockIdx.y * 32;
  int tx = threadIdx.x, ty = threadIdx.y;   // blockDim (32,8)
  #pragma unroll
  for (int i = 0; i < 32; i += 8)
    tile[ty + i][tx] = src[(size_t)(k0 + ty + i) * N + n0 + tx];
  __syncthreads();
  #pragma unroll
  for (int i = 0; i < 32; i += 8)
    dst[(size_t)(n0 + ty + i) * dstLd + k0 + tx] = f2b(tile[tx][ty + i]);
}

// ---------------- w2 -> fp8 register layout: one byte per thread -----------------------
// w2r[((chunk*4 + cg)*4 + i)*1024 + lane*16 + kh*8 + b] = fp8(256 * w2[e][hL][c])
//   e = chunk>>4, hL = (chunk&15)*64 + kh*32 + (lane>>4)*8 + b, c = cg*64 + i*16 + (lane&15)
// Down-wave loads its MFMA A-operands as ONE coalesced dwordx4 per (i):
//   16B = [kk=0: 8 fp8 k-values][kk=1: 8 fp8], per lane.  Layout/numerics HW-verified
//   (R8/R9 passed with absmax 0.03125 using this exact prep + MFMA pairing).
__global__ __launch_bounds__(256) void prep_w2r(
    const float* __restrict__ src, unsigned char* __restrict__ dst) {
  int flat = blockIdx.x * 256 + threadIdx.x;     // 0 .. 1M
  int b    = flat & 7;
  int kh   = (flat >> 3) & 1;
  int lane = (flat >> 4) & 63;
  int i    = (flat >> 10) & 3;
  int cg   = (flat >> 12) & 3;
  int chunk= (flat >> 14) & 63;
  int quad = lane >> 4, lm = lane & 15;
  int e    = chunk >> 4;
  int hL   = (chunk & 15) * 64 + kh * 32 + quad * 8 + b;
  int c    = cg * 64 + i * 16 + lm;
  dst[flat] = f2fp8(src[((size_t)e * H_ + hL) * C_ + c] * 256.0f);
}

// ---------------- LayerNorm 1 ----------------
__global__ __launch_bounds__(256) void ln1_kernel(
    const float* __restrict__ x, const float* __restrict__ g,
    const float* __restrict__ b, unsigned short* __restrict__ h) {
  __shared__ float red[4];
  int row = blockIdx.x, tid = threadIdx.x;
  float v = x[(size_t)row * C_ + tid];
  float s = v;
  #pragma unroll
  for (int o = 32; o; o >>= 1) s += __shfl_xor(s, o);
  if ((tid & 63) == 0) red[tid >> 6] = s;
  __syncthreads();
  float mean = (red[0] + red[1] + red[2] + red[3]) * (1.0f / C_);
  __syncthreads();
  float d = v - mean;
  float q = d * d;
  #pragma unroll
  for (int o = 32; o; o >>= 1) q += __shfl_xor(q, o);
  if ((tid & 63) == 0) red[tid >> 6] = q;
  __syncthreads();
  float var = (red[0] + red[1] + red[2] + red[3]) * (1.0f / C_);
  h[(size_t)row * C_ + tid] = f2b(d * rsqrtf(var + 1e-5f) * g[tid] + b[tid]);
}

// ---------------- LayerNorm 2 + gating softmax (h2 bf16) ----------------
__global__ __launch_bounds__(256) void ln2_gates_kernel(
    const float* __restrict__ x1, const float* __restrict__ g,
    const float* __restrict__ b, const float* __restrict__ gw,
    const float* __restrict__ gb, unsigned short* __restrict__ h2,
    float* __restrict__ gates) {
  __shared__ float red[4];
  __shared__ float redg[4][4];
  int row = blockIdx.x, tid = threadIdx.x;
  float v = x1[(size_t)row * C_ + tid];
  float s = v;
  #pragma unroll
  for (int o = 32; o; o >>= 1) s += __shfl_xor(s, o);
  if ((tid & 63) == 0) red[tid >> 6] = s;
  __syncthreads();
  float mean = (red[0] + red[1] + red[2] + red[3]) * (1.0f / C_);
  __syncthreads();
  float d = v - mean;
  float q = d * d;
  #pragma unroll
  for (int o = 32; o; o >>= 1) q += __shfl_xor(q, o);
  if ((tid & 63) == 0) red[tid >> 6] = q;
  __syncthreads();
  float var = (red[0] + red[1] + red[2] + red[3]) * (1.0f / C_);
  float hv = d * rsqrtf(var + 1e-5f) * g[tid] + b[tid];
  h2[(size_t)row * C_ + tid] = f2b(hv);
  float p0 = hv * gw[tid * 4 + 0];
  float p1 = hv * gw[tid * 4 + 1];
  float p2 = hv * gw[tid * 4 + 2];
  float p3 = hv * gw[tid * 4 + 3];
  #pragma unroll
  for (int o = 32; o; o >>= 1) {
    p0 += __shfl_xor(p0, o); p1 += __shfl_xor(p1, o);
    p2 += __shfl_xor(p2, o); p3 += __shfl_xor(p3, o);
  }
  if ((tid & 63) == 0) {
    int w = tid >> 6;
    redg[w][0] = p0; redg[w][1] = p1; redg[w][2] = p2; redg[w][3] = p3;
  }
  __syncthreads();
  if (tid == 0) {
    float t4[4];
    #pragma unroll
    for (int e = 0; e < 4; e++)
      t4[e] = redg[0][e] + redg[1][e] + redg[2][e] + redg[3][e] + gb[e];
    float m = fmaxf(fmaxf(t4[0], t4[1]), fmaxf(t4[2], t4[3]));
    float zs = 0.f;
    #pragma unroll
    for (int e = 0; e < 4; e++) { t4[e] = __expf(t4[e] - m); zs += t4[e]; }
    float inv = 1.0f / zs;
    #pragma unroll
    for (int e = 0; e < 4; e++) gates[(size_t)row * 4 + e] = t4[e] * inv;
  }
}

// ---------------- chunked prefix scan of v ----------------
__global__ __launch_bounds__(256) void scan1_kernel(const unsigned short* __restrict__ qkv,
                                                    float* __restrict__ S) {
  int b = blockIdx.x >> 6, ch = blockIdx.x & 63, c = threadIdx.x;
  float s = 0.f;
  size_t base = ((size_t)b * T_ + (size_t)ch * CHL_) * C3_ + 512 + c;
  for (int t = 0; t < CHL_; t++) s += b2f(qkv[base + (size_t)t * C3_]);
  S[((size_t)b * NCH_ + ch) * C_ + c] = s;
}
__global__ __launch_bounds__(256) void scan2_kernel(float* __restrict__ S) {
  int b = blockIdx.x, c = threadIdx.x;
  float run = 0.f;
  for (int ch = 0; ch < NCH_; ch++) {
    size_t i = ((size_t)b * NCH_ + ch) * C_ + c;
    float t = S[i]; S[i] = run; run += t;
  }
}
__global__ __launch_bounds__(256) void scan3_kernel(const unsigned short* __restrict__ qkv,
                                                    const float* __restrict__ S,
                                                    unsigned short* __restrict__ Pb) {
  int b = blockIdx.x >> 6, ch = blockIdx.x & 63, c = threadIdx.x;
  float run = S[((size_t)b * NCH_ + ch) * C_ + c];
  size_t row0 = (size_t)b * T_ + (size_t)ch * CHL_;
  for (int t = 0; t < CHL_; t++) {
    run += b2f(qkv[(row0 + t) * C3_ + 512 + c]);
    Pb[(row0 + t) * C_ + c] = f2b(run);
  }
}

// ---------------- windowed attention: 16-lane group per window position ----------------
__global__ __launch_bounds__(256) void attn_kernel(
    const unsigned short* __restrict__ qkv, const unsigned short* __restrict__ Pb,
    const float* __restrict__ gate, unsigned short* __restrict__ aout) {
  int wave = threadIdx.x >> 6, lane = threadIdx.x & 63;
  int r = blockIdx.x * 4 + wave;
  int t = r & (T_ - 1);
  int g = lane >> 4, u = lane & 15;
  const unsigned short* qp = qkv + (size_t)r * C3_ + (u << 4);
  float qv[16];
  unpack8(*(const uint4*)qp, qv);
  unpack8(*(const uint4*)(qp + 8), qv + 8);
  float sc[5];
  #pragma unroll
  for (int rnd = 0; rnd < 5; rnd++) {
    int j = rnd * 4 + g;
    int jj = t - 16 + j;
    bool valid = (j <= 16) && (jj >= 0);
    float d = 0.f;
    if (valid) {
      const unsigned short* kp = qkv + (size_t)(r - 16 + j) * C3_ + 256 + (u << 4);
      float kv[16];
      unpack8(*(const uint4*)kp, kv);
      unpack8(*(const uint4*)(kp + 8), kv + 8);
      #pragma unroll
      for (int c = 0; c < 16; c++) d += qv[c] * kv[c];
    }
    d += __shfl_xor(d, 1); d += __shfl_xor(d, 2);
    d += __shfl_xor(d, 4); d += __shfl_xor(d, 8);
    sc[rnd] = valid ? d * 0.0625f : -1e30f;
  }
  float m = fmaxf(fmaxf(fmaxf(sc[0], sc[1]), fmaxf(sc[2], sc[3])), sc[4]);
  m = fmaxf(m, __shfl_xor(m, 16));
  m = fmaxf(m, __shfl_xor(m, 32));
  if (t > 16) m = fmaxf(m, 0.0f);
  float ev[5], Zp = 0.f;
  #pragma unroll
  for (int rnd = 0; rnd < 5; rnd++) {
    ev[rnd] = (sc[rnd] > -1e29f) ? __expf(sc[rnd] - m) : 0.f;
    Zp += ev[rnd];
  }
  Zp += __shfl_xor(Zp, 16);
  Zp += __shfl_xor(Zp, 32);
  float e0v = 0.f;
  if (t > 16) { e0v = __expf(-m); Zp += e0v * (float)(t - 16); }
  float vp[16];
  #pragma unroll
  for (int c = 0; c < 16; c++) vp[c] = 0.f;
  #pragma unroll
  for (int rnd = 0; rnd < 5; rnd++) {
    if (ev[rnd] != 0.f) {
      int j = rnd * 4 + g;
      const unsigned short* vpp = qkv + (size_t)(r - 16 + j) * C3_ + 512 + (u << 4);
      float vv[16];
      unpack8(*(const uint4*)vpp, vv);
      unpack8(*(const uint4*)(vpp + 8), vv + 8);
      #pragma unroll
      for (int c = 0; c < 16; c++) vp[c] += ev[rnd] * vv[c];
    }
  }
  #pragma unroll
  for (int c = 0; c < 16; c++) {
    vp[c] += __shfl_xor(vp[c], 16);
    vp[c] += __shfl_xor(vp[c], 32);
  }
  if (g == 0) {
    if (t > 16) {
      const unsigned short* pp = Pb + (size_t)(r - 17) * C_ + (u << 4);
      float pv[16];
      unpack8(*(const uint4*)pp, pv);
      unpack8(*(const uint4*)(pp + 8), pv + 8);
      #pragma unroll
      for (int c = 0; c < 16; c++) vp[c] += e0v * pv[c];
    }
    float inv = 1.0f / Zp;
    const float* gp = gate + (u << 4);
    unsigned int ow[8];
    #pragma unroll
    for (int i = 0; i < 8; i++) {
      unsigned short lo = f2b(vp[2*i] * inv * gp[2*i]);
      unsigned short hi = f2b(vp[2*i+1] * inv * gp[2*i+1]);
      ow[i] = (unsigned int)lo | ((unsigned int)hi << 16);
    }
    uint4 s0 = {ow[0], ow[1], ow[2], ow[3]};
    uint4 s1 = {ow[4], ow[5], ow[6], ow[7]};
    *(uint4*)(aout + (size_t)r * C_ + (u << 4)) = s0;
    *(uint4*)(aout + (size_t)r * C_ + (u << 4) + 8) = s1;
  }
}

// ---------------- 128x128 MFMA GEMM, operand-swapped, swizzled staging ------------------
// EPI 0: outb = bf16(acc + bias)                              (qkv)
// EPI 1: x1 = acc + bias + resid                              (proj)
template<int EPI>
__global__ __launch_bounds__(256) void gemm128(
    const unsigned short* __restrict__ A, const unsigned short* __restrict__ Bt,
    const float* __restrict__ bias, int K, int ldOut,
    const float* __restrict__ resid, float* __restrict__ outf,
    unsigned short* __restrict__ outb) {
  __shared__ __align__(16) unsigned short As[128 * 64];
  __shared__ __align__(16) unsigned short Bs[128 * 64];
  const int tid = threadIdx.x;
  const int wave = tid >> 6, lane = tid & 63;
  const int mBlk = blockIdx.x * 128, nBlk = blockIdx.y * 128;
  const int wm = (wave >> 1) * 64, wn = (wave & 1) * 64;
  const int lm = lane & 15, lk = (lane >> 4) * 8;
  floatx4 acc[4][4];
  #pragma unroll
  for (int i = 0; i < 4; i++)
    #pragma unroll
    for (int j = 0; j < 4; j++) acc[i][j] = (floatx4){0.f, 0.f, 0.f, 0.f};

  for (int kt = 0; kt < K; kt += 64) {
    __syncthreads();
    #pragma unroll
    for (int i = 0; i < 4; i++) {
      int seg = i * 256 + tid;          // 16B segment index
      int row = seg >> 3, g = seg & 7;
      int gc = (g ^ (row & 7)) << 3;    // XOR-swizzle the GLOBAL column (LDS stays linear)
      gl_lds16(A + (size_t)(mBlk + row) * K + kt + gc, &As[seg * 8]);
      gl_lds16(Bt + (size_t)(nBlk + row) * K + kt + gc, &Bs[seg * 8]);
    }
    __syncthreads();
    #pragma unroll
    for (int kk = 0; kk < 64; kk += 32) {
      short8 mf[4], nf[4];
      #pragma unroll
      for (int j = 0; j < 4; j++) {
        int row = wm + j * 16 + lm;
        mf[j] = *(const short8*)&As[row * 64 + ((((kk + lk) >> 3) ^ (row & 7)) << 3)];
      }
      #pragma unroll
      for (int i = 0; i < 4; i++) {
        int row = wn + i * 16 + lm;
        nf[i] = *(const short8*)&Bs[row * 64 + ((((kk + lk) >> 3) ^ (row & 7)) << 3)];
      }
      #pragma unroll
      for (int i = 0; i < 4; i++)
        #pragma unroll
        for (int j = 0; j < 4; j++)
          acc[i][j] = __builtin_amdgcn_mfma_f32_16x16x32_bf16(nf[i], mf[j], acc[i][j], 0, 0, 0);
    }
  }
  const int lc = lane & 15, quad = lane >> 4, q4 = quad * 4;
  #pragma unroll
  for (int i = 0; i < 4; i++) {
    int n0 = nBlk + wn + i * 16 + q4;
    float4 bs = *(const float4*)&bias[n0];
    #pragma unroll
    for (int j = 0; j < 4; j++) {
      int m = mBlk + wm + j * 16 + lc;
      float v0 = acc[i][j][0] + bs.x, v1 = acc[i][j][1] + bs.y;
      float v2 = acc[i][j][2] + bs.z, v3 = acc[i][j][3] + bs.w;
      if (EPI == 0) {
        ushort4 o = {f2b(v0), f2b(v1), f2b(v2), f2b(v3)};
        *(ushort4*)&outb[(size_t)m * ldOut + n0] = o;
      } else {
        size_t idx = (size_t)m * ldOut + n0;
        float4 r = *(const float4*)&resid[idx];
        float4 o = {v0 + r.x, v1 + r.y, v2 + r.z, v3 + r.w};
        *(float4*)&outf[idx] = o;
      }
    }
  }
}

// ---------------- fused MoE, 12 waves (4 up + 8 down), 3 waves/SIMD ---------------------
// Grid 256, 64 rows/block, 64 chunks of 64 hid.  768 threads = 12 waves:
//   waves 0-3  up:   16m x 64h each (af[8] = 32 VGPR), gelu+gate+fp8 -> Hs
//   waves 4-11 down: 64m x 32c each (dacc[2][4] = 32 AGPR, w2reg[2] = 8 VGPR)
// Unified VGPR/AGPR budget (the R4/R8/R9 spill cause): union ~80 VGPR + 48 AGPR = ~130
// <= 170 (= 512/3 at 3 waves/SIMD) -> no spill.  LDS = W1s dbuf 64K + Hs dbuf 8K = 72 KB.
// __launch_bounds__(768,3): 12 waves/CU = 3/SIMD (1 up + 2 down per SIMD).
// Single-barrier schedule (R7-verified): barrier -> stage-issue -> compute -> vmcnt(0).
__global__ __launch_bounds__(768, 3) void moe_fused(
    const unsigned short* __restrict__ h2,   // [M,256] bf16
    const unsigned short* __restrict__ w1t,  // [4096,256] bf16
    const float* __restrict__ b1,            // [4096] flat
    const unsigned char* __restrict__ w2r,   // [64][4][4][64][16] fp8 reg layout (x256)
    const float* __restrict__ b2,            // [4][256]
    const float* __restrict__ gates,         // [M,4]
    const float* __restrict__ x1,            // [M,256]
    float* __restrict__ out) {
  __shared__ __align__(16) unsigned short W1s[2][64 * 256];    // 64 KB
  __shared__ __align__(16) unsigned char  Hs[2][64 * 64];      // 8 KB
  const int tid = threadIdx.x;
  const int wave = tid >> 6, lane = tid & 63;
  const int lm = lane & 15, quad = lane >> 4;
  const int mb = blockIdx.x * 64;
  const bool isUp = wave < 4;
  const int wmu = (wave & 3) * 16;    // up-tile m offset (16 rows per up wave)
  const int dw  = wave - 4;           // down wave index 0..7 (c offset dw*32)

  // stage W1 chunk c into buffer buf: <=3 gl_lds/wave (t=2 is wave-uniform partial)
  auto stageW1 = [&](int c, int buf) {
    const unsigned short* ws = w1t + (size_t)c * 64 * C_;
    #pragma unroll
    for (int t = 0; t < 3; t++) {
      int seg = t * 768 + tid;
      if (seg < 2048) {                // t=2: tid<512 -> waves 0-7 full, 8-11 skip (uniform)
        int row = seg >> 5, g = seg & 31;
        int gp = (g & 24) | ((g & 7) ^ (row & 7));
        gl_lds16(ws + (size_t)row * C_ + gp * 8, &W1s[buf][seg * 8]);
      }
    }
  };

  stageW1(0, 0);

  // A-fragments -> registers (up waves): h2 rows [mb+wmu, +16), reused 64 chunks.
  short8 af[8];
  float4 ga;
  if (isUp) {
    int row = mb + wmu + lm;
    #pragma unroll
    for (int kk = 0; kk < 8; kk++)
      af[kk] = *(const short8*)(h2 + (size_t)row * C_ + (kk * 4 + quad) * 8);
    ga = *(const float4*)(gates + (size_t)row * 4);
  }

  long2v w2reg[2];      // down waves: W2 fragments for the chunk consumed NEXT iter
  floatx4 dacc[2][4];   // [i = c-frag (2x16 cols)][j = m-frag], down waves only
  #pragma unroll
  for (int i = 0; i < 2; i++)
    #pragma unroll
    for (int j = 0; j < 4; j++) dacc[i][j] = (floatx4){0.f, 0.f, 0.f, 0.f};

  // prologue: own chunk-0 stage (and af/ga loads) landed before first barrier
  asm volatile("s_waitcnt vmcnt(0)" ::: "memory");

  for (int c = 0; c < 64; c++) {
    const int wb = c & 1;
    // single barrier: everyone's prev-iter stages landed (own vmcnt(0) before arrival)
    // and everyone finished compute(c-1) -> restage + read both safe
    __builtin_amdgcn_s_barrier();
    __builtin_amdgcn_sched_barrier(0);
    stageW1((c + 1) & 63, wb ^ 1);     // W1 for chunk c+1 (wrap harmless)

    if (isUp) {
      // ---- up-GEMM chunk c: uacc[i] = h2[16m] x w1[64h], K=256
      floatx4 uacc[4];
      #pragma unroll
      for (int i = 0; i < 4; i++) uacc[i] = (floatx4){0.f, 0.f, 0.f, 0.f};
      __builtin_amdgcn_s_setprio(1);
      #pragma unroll
      for (int kk = 0; kk < 8; kk++) {
        int kc = kk * 4 + quad;
        #pragma unroll
        for (int i = 0; i < 4; i++) {
          int row = i * 16 + lm;
          short8 nf = *(const short8*)&W1s[wb][row * 256 + ((kc ^ (row & 7)) << 3)];
          uacc[i] = __builtin_amdgcn_mfma_f32_16x16x32_bf16(nf, af[kk], uacc[i], 0, 0, 0);
        }
      }
      __builtin_amdgcn_s_setprio(0);
      // ---- gelu + gate + fp8 -> Hs[wb], XOR-swizzled 8B granules (b1 direct, L2-hot)
      float gs = 64.0f * sel4(ga, c >> 4);
      int m = wmu + lm;
      #pragma unroll
      for (int i = 0; i < 4; i++) {
        float4 bb = *(const float4*)&b1[(size_t)c * 64 + i * 16 + quad * 4];
        unsigned int w = pk_fp8x4(gs * gelu_s(uacc[i][0] + bb.x),
                                  gs * gelu_s(uacc[i][1] + bb.y),
                                  gs * gelu_s(uacc[i][2] + bb.z),
                                  gs * gelu_s(uacc[i][3] + bb.w));
        int hh = i * 16 + quad * 4;
        *(unsigned int*)&Hs[wb][m * 64 + ((((hh >> 3) ^ (m & 7)) << 3) | (hh & 7))] = w;
      }
      asm volatile("s_waitcnt lgkmcnt(0)" ::: "memory");   // Hs writes landed before barrier
    } else {
      if (c > 0) {
        // ---- down-GEMM chunk c-1: dacc += hid8[64m x 64k] x w2[32c x 64k] (fp8)
        const int pb = wb ^ 1;
        __builtin_amdgcn_s_setprio(1);
        #pragma unroll
        for (int kk = 0; kk < 2; kk++) {
          long mfh[4];
          #pragma unroll
          for (int j = 0; j < 4; j++) {
            int m = j * 16 + lm;
            int g8 = quad + 4 * kk;
            mfh[j] = *(const long*)&Hs[pb][m * 64 + ((g8 ^ (m & 7)) << 3)];
          }
          #pragma unroll
          for (int i = 0; i < 2; i++)
            #pragma unroll
            for (int j = 0; j < 4; j++)
              dacc[i][j] = __builtin_amdgcn_mfma_f32_16x16x32_fp8_fp8(w2reg[i][kk], mfh[j], dacc[i][j], 0, 0, 0);
        }
        __builtin_amdgcn_s_setprio(0);
      }
      // load W2 fragments for chunk c (consumed next iter / drain): global frag index
      // i_g = (dw&1)*2 + i within c-group cg = dw>>1.  Issued AFTER the MFMAs that read
      // the old regs (WAR via register dataflow); drained by vmcnt(0).
      const unsigned char* vs = w2r +
          ((size_t)(c * 4 + (dw >> 1)) * 4 + (dw & 1) * 2) * 1024 + lane * 16;
      #pragma unroll
      for (int i = 0; i < 2; i++)
        w2reg[i] = *(const long2v*)(vs + (size_t)i * 1024);
    }
    // own stage/reg loads landed before announcing arrival at the next barrier
    asm volatile("s_waitcnt vmcnt(0)" ::: "memory");
  }

  // ---- drain: final down step for chunk 63 (Hs[1], w2reg), then epilogue
  __builtin_amdgcn_s_barrier();
  __builtin_amdgcn_sched_barrier(0);
  if (!isUp) {
    #pragma unroll
    for (int kk = 0; kk < 2; kk++) {
      long mfh[4];
      #pragma unroll
      for (int j = 0; j < 4; j++) {
        int m = j * 16 + lm;
        int g8 = quad + 4 * kk;
        mfh[j] = *(const long*)&Hs[1][m * 64 + ((g8 ^ (m & 7)) << 3)];
      }
      #pragma unroll
      for (int i = 0; i < 2; i++)
        #pragma unroll
        for (int j = 0; j < 4; j++)
          dacc[i][j] = __builtin_amdgcn_mfma_f32_16x16x32_fp8_fp8(w2reg[i][kk], mfh[j], dacc[i][j], 0, 0, 0);
    }
    // ---- epilogue: out = dacc/2^14 + x1 + sum_e gate_e * b2_e  (this wave's 32 cols)
    const float sc = 1.0f / 16384.0f;
    const int q4 = quad * 4;
    #pragma unroll
    for (int j = 0; j < 4; j++) {
      int m = mb + j * 16 + lm;
      float4 g4 = *(const float4*)(gates + (size_t)m * 4);
      #pragma unroll
      for (int i = 0; i < 2; i++) {
        int n0 = dw * 32 + i * 16 + q4;
        float4 bA = *(const float4*)&b2[0 * C_ + n0];
        float4 bB = *(const float4*)&b2[1 * C_ + n0];
        float4 bC = *(const float4*)&b2[2 * C_ + n0];
        float4 bD = *(const float4*)&b2[3 * C_ + n0];
        size_t idx = (size_t)m * C_ + n0;
        float4 r = *(const float4*)&x1[idx];
        float4 o;
        o.x = dacc[i][j][0]*sc + r.x + g4.x*bA.x + g4.y*bB.x + g4.z*bC.x + g4.w*bD.x;
        o.y = dacc[i][j][1]*sc + r.y + g4.x*bA.y + g4.y*bB.y + g4.z*bC.y + g4.w*bD.y;
        o.z = dacc[i][j][2]*sc + r.z + g4.x*bA.z + g4.y*bB.z + g4.z*bC.z + g4.w*bD.z;
        o.w = dacc[i][j][3]*sc + r.w + g4.x*bA.w + g4.y*bB.w + g4.z*bC.w + g4.w*bD.w;
        *(float4*)&out[idx] = o;
      }
    }
  }
}

extern "C" void kernel_launch(void* const* d_in, const int* in_sizes, int n_in,
                              void* d_out, int out_size, void* d_ws, size_t ws_size,
                              hipStream_t stream) {
  const float* x       = (const float*)d_in[0];
  const float* ln1_g   = (const float*)d_in[1];
  const float* ln1_b   = (const float*)d_in[2];
  const float* qkv_w   = (const float*)d_in[3];
  const float* qkv_b   = (const float*)d_in[4];
  const float* proj_w  = (const float*)d_in[5];
  const float* proj_b  = (const float*)d_in[6];
  const float* attn_g  = (const float*)d_in[7];
  const float* ln2_g   = (const float*)d_in[8];
  const float* ln2_b   = (const float*)d_in[9];
  const float* gat_w   = (const float*)d_in[10];
  const float* gat_b   = (const float*)d_in[11];
  const float* e_w1    = (const float*)d_in[12];
  const float* e_b1    = (const float*)d_in[13];
  const float* e_w2    = (const float*)d_in[14];
  const float* e_b2    = (const float*)d_in[15];
  float* out = (float*)d_out;

  char* p = (char*)d_ws;
  unsigned short* h    = (unsigned short*)p; p += (size_t)M_ * C_ * 2;      // 8 MB
  unsigned short* qkv  = (unsigned short*)p; p += (size_t)M_ * C3_ * 2;     // 24 MB
  unsigned short* Pb   = (unsigned short*)p; p += (size_t)M_ * C_ * 2;      // 8 MB
  unsigned short* aout = (unsigned short*)p; p += (size_t)M_ * C_ * 2;      // 8 MB
  float*          x1   = (float*)p;          p += (size_t)M_ * C_ * 4;      // 16 MB
  unsigned short* h2   = (unsigned short*)p; p += (size_t)M_ * C_ * 2;      // 8 MB
  float*          gts  = (float*)p;          p += (size_t)M_ * E_ * 4;      // 256 KB
  float*          S    = (float*)p;          p += (size_t)B_ * NCH_ * C_ * 4;
  unsigned short* wq   = (unsigned short*)p; p += (size_t)C3_ * C_ * 2;
  unsigned short* wp   = (unsigned short*)p; p += (size_t)C_ * C_ * 2;
  unsigned short* w1t  = (unsigned short*)p; p += (size_t)KH_ * C_ * 2;     // 2 MB [4096,256]
  unsigned char*  w2r  = (unsigned char*)p;  p += (size_t)C_ * KH_;         // 1 MB reg layout

  dim3 t32x8(32, 8);
  transpose_cvt<<<dim3(C3_/32, C_/32, 1), t32x8, 0, stream>>>(qkv_w, wq, C_, C3_, C_, 0);
  transpose_cvt<<<dim3(C_/32, C_/32, 1),  t32x8, 0, stream>>>(proj_w, wp, C_, C_, C_, 0);
  // w1t[e*1024 + hrow][c]  (flat [4096, 256]) bf16
  transpose_cvt<<<dim3(H_/32, C_/32, E_), t32x8, 0, stream>>>(e_w1, w1t, C_, H_, C_, (size_t)H_ * C_);
  // w2 -> fp8 x256, register layout for direct per-wave dwordx4 loads
  prep_w2r<<<4096, 256, 0, stream>>>(e_w2, w2r);

  ln1_kernel<<<M_, 256, 0, stream>>>(x, ln1_g, ln1_b, h);
  gemm128<0><<<dim3(M_/128, C3_/128), 256, 0, stream>>>(h, wq, qkv_b, C_, C3_,
      nullptr, nullptr, qkv);
  scan1_kernel<<<B_*NCH_, 256, 0, stream>>>(qkv, S);
  scan2_kernel<<<B_, 256, 0, stream>>>(S);
  scan3_kernel<<<B_*NCH_, 256, 0, stream>>>(qkv, S, Pb);
  attn_kernel<<<M_/4, 256, 0, stream>>>(qkv, Pb, attn_g, aout);
  // x1 = x + aout @ proj_w + proj_b
  gemm128<1><<<dim3(M_/128, C_/128), 256, 0, stream>>>(aout, wp, proj_b, C_, C_,
      x, x1, nullptr);
  ln2_gates_kernel<<<M_, 256, 0, stream>>>(x1, ln2_g, ln2_b, gat_w, gat_b, h2, gts);
  // fused MoE: 12 waves (4 up + 8 down), 72 KB LDS, 3 waves/SIMD
  moe_fused<<<M_/64, 768, 0, stream>>>(h2, w1t, e_b1, w2r, e_b2, gts, x1, out);
}

// Round 11
// 319.471 us; speedup vs baseline: 1.7009x; 1.0362x over previous
//
#include <hip/hip_runtime.h>
#include <hip/hip_bf16.h>
#include <math.h>

#define T_   4096
#define B_   4
#define C_   256
#define C3_  768
#define H_   1024
#define E_   4
#define M_   (B_*T_)      // 16384 rows
#define NCH_ 64
#define CHL_ (T_/NCH_)    // 64
#define KH_  4096         // E*H

typedef __attribute__((ext_vector_type(8))) short short8;
typedef __attribute__((ext_vector_type(4))) float floatx4;

__device__ __forceinline__ float b2f(unsigned short u) {
  union { unsigned int i; float f; } x; x.i = ((unsigned int)u) << 16; return x.f;
}
__device__ __forceinline__ unsigned short f2b(float f) {
  __hip_bfloat16 h = __float2bfloat16(f);
  return *reinterpret_cast<unsigned short*>(&h);
}
__device__ __forceinline__ void unpack8(uint4 a, float* f) {
  unsigned int w[4] = {a.x, a.y, a.z, a.w};
  #pragma unroll
  for (int i = 0; i < 4; i++) {
    union { unsigned int u; float g; } lo, hi;
    lo.u = w[i] << 16; hi.u = w[i] & 0xffff0000u;
    f[2*i] = lo.g; f[2*i+1] = hi.g;
  }
}
__device__ __forceinline__ void gl_lds16(const void* g, void* l) {
  __builtin_amdgcn_global_load_lds(
      (const __attribute__((address_space(1))) void*)g,
      (__attribute__((address_space(3))) void*)l, 16, 0, 0);
}
// sigmoid GELU: x*sigma(1.702x). |err|<=~0.01 on hid; attenuated by zero-mean w2 down-sum.
// Numerics verified on HW: passed with absmax 0.03125 using this form.
__device__ __forceinline__ float gelu_s(float v) {
  float e = __expf(-1.702f * v);
  return v * __builtin_amdgcn_rcpf(1.0f + e);
}
// pack 4 floats -> 4 fp8 e4m3 (OCP) in one uint
__device__ __forceinline__ unsigned int pk_fp8x4(float a, float b, float c, float d) {
  unsigned int v = 0;
  v = __builtin_amdgcn_cvt_pk_fp8_f32(a, b, v, false);
  v = __builtin_amdgcn_cvt_pk_fp8_f32(c, d, v, true);
  return v;
}
__device__ __forceinline__ unsigned char f2fp8(float v) {
  return (unsigned char)(__builtin_amdgcn_cvt_pk_fp8_f32(v, v, 0, false) & 0xff);
}
__device__ __forceinline__ float sel4(float4 v, int e) {
  float r = v.x;
  r = (e == 1) ? v.y : r;
  r = (e == 2) ? v.z : r;
  r = (e == 3) ? v.w : r;
  return r;
}

// ---------------- transpose + fp32->bf16: src[K,N](+z*K*N) -> dst[+z*zStr][n*dstLd + k] ----
__global__ __launch_bounds__(256) void transpose_cvt(
    const float* __restrict__ src, unsigned short* __restrict__ dst, int K, int N,
    int dstLd, size_t dstZStride) {
  __shared__ float tile[32][33];
  src += (size_t)blockIdx.z * K * N;
  dst += (size_t)blockIdx.z * dstZStride;
  int n0 = blockIdx.x * 32, k0 = blockIdx.y * 32;
  int tx = threadIdx.x, ty = threadIdx.y;   // blockDim (32,8)
  #pragma unroll
  for (int i = 0; i < 32; i += 8)
    tile[ty + i][tx] = src[(size_t)(k0 + ty + i) * N + n0 + tx];
  __syncthreads();
  #pragma unroll
  for (int i = 0; i < 32; i += 8)
    dst[(size_t)(n0 + ty + i) * dstLd + k0 + tx] = f2b(tile[tx][ty + i]);
}

// ---------------- w2 -> fp8 blocked: w2b[chunk=k>>6][c][64 bytes, seg-swizzled] ----------
// value = fp8(w2[e][h][c] * 256), k = e*1024+h.  Within the 64-byte row the 16B seg s
// is stored at s ^ ((c>>2)&3): down-GEMM b64 read bank = 16(c&1)+4(s^((c>>2)&3))+2(q&1)
// -> (c&1,(c>>2)&3) takes 8 distinct values over 16 lanes = 2-way (free).
__global__ __launch_bounds__(256) void transpose_w2_fp8(
    const float* __restrict__ src, unsigned char* __restrict__ dst) {
  __shared__ float tile[32][33];
  int e = blockIdx.z;
  src += (size_t)e * H_ * C_;
  int h0 = blockIdx.x * 32, c0 = blockIdx.y * 32;
  int tx = threadIdx.x, ty = threadIdx.y;
  #pragma unroll
  for (int i = 0; i < 32; i += 8)
    tile[ty + i][tx] = src[(size_t)(h0 + ty + i) * C_ + c0 + tx];
  __syncthreads();
  int k = e * H_ + h0 + tx;
  int chunk = k >> 6, kc = k & 63;
  #pragma unroll
  for (int i = 0; i < 32; i += 8) {
    int c = c0 + ty + i;
    int sw = ((((kc >> 4) ^ ((c >> 2) & 3)) << 4) | (kc & 15));
    dst[((size_t)chunk * 256 + c) * 64 + sw] = f2fp8(tile[tx][ty + i] * 256.0f);
  }
}

// ---------------- LayerNorm 1 ----------------
__global__ __launch_bounds__(256) void ln1_kernel(
    const float* __restrict__ x, const float* __restrict__ g,
    const float* __restrict__ b, unsigned short* __restrict__ h) {
  __shared__ float red[4];
  int row = blockIdx.x, tid = threadIdx.x;
  float v = x[(size_t)row * C_ + tid];
  float s = v;
  #pragma unroll
  for (int o = 32; o; o >>= 1) s += __shfl_xor(s, o);
  if ((tid & 63) == 0) red[tid >> 6] = s;
  __syncthreads();
  float mean = (red[0] + red[1] + red[2] + red[3]) * (1.0f / C_);
  __syncthreads();
  float d = v - mean;
  float q = d * d;
  #pragma unroll
  for (int o = 32; o; o >>= 1) q += __shfl_xor(q, o);
  if ((tid & 63) == 0) red[tid >> 6] = q;
  __syncthreads();
  float var = (red[0] + red[1] + red[2] + red[3]) * (1.0f / C_);
  h[(size_t)row * C_ + tid] = f2b(d * rsqrtf(var + 1e-5f) * g[tid] + b[tid]);
}

// ---------------- LayerNorm 2 + gating softmax (h2 bf16) ----------------
__global__ __launch_bounds__(256) void ln2_gates_kernel(
    const float* __restrict__ x1, const float* __restrict__ g,
    const float* __restrict__ b, const float* __restrict__ gw,
    const float* __restrict__ gb, unsigned short* __restrict__ h2,
    float* __restrict__ gates) {
  __shared__ float red[4];
  __shared__ float redg[4][4];
  int row = blockIdx.x, tid = threadIdx.x;
  float v = x1[(size_t)row * C_ + tid];
  float s = v;
  #pragma unroll
  for (int o = 32; o; o >>= 1) s += __shfl_xor(s, o);
  if ((tid & 63) == 0) red[tid >> 6] = s;
  __syncthreads();
  float mean = (red[0] + red[1] + red[2] + red[3]) * (1.0f / C_);
  __syncthreads();
  float d = v - mean;
  float q = d * d;
  #pragma unroll
  for (int o = 32; o; o >>= 1) q += __shfl_xor(q, o);
  if ((tid & 63) == 0) red[tid >> 6] = q;
  __syncthreads();
  float var = (red[0] + red[1] + red[2] + red[3]) * (1.0f / C_);
  float hv = d * rsqrtf(var + 1e-5f) * g[tid] + b[tid];
  h2[(size_t)row * C_ + tid] = f2b(hv);
  float p0 = hv * gw[tid * 4 + 0];
  float p1 = hv * gw[tid * 4 + 1];
  float p2 = hv * gw[tid * 4 + 2];
  float p3 = hv * gw[tid * 4 + 3];
  #pragma unroll
  for (int o = 32; o; o >>= 1) {
    p0 += __shfl_xor(p0, o); p1 += __shfl_xor(p1, o);
    p2 += __shfl_xor(p2, o); p3 += __shfl_xor(p3, o);
  }
  if ((tid & 63) == 0) {
    int w = tid >> 6;
    redg[w][0] = p0; redg[w][1] = p1; redg[w][2] = p2; redg[w][3] = p3;
  }
  __syncthreads();
  if (tid == 0) {
    float t4[4];
    #pragma unroll
    for (int e = 0; e < 4; e++)
      t4[e] = redg[0][e] + redg[1][e] + redg[2][e] + redg[3][e] + gb[e];
    float m = fmaxf(fmaxf(t4[0], t4[1]), fmaxf(t4[2], t4[3]));
    float zs = 0.f;
    #pragma unroll
    for (int e = 0; e < 4; e++) { t4[e] = __expf(t4[e] - m); zs += t4[e]; }
    float inv = 1.0f / zs;
    #pragma unroll
    for (int e = 0; e < 4; e++) gates[(size_t)row * 4 + e] = t4[e] * inv;
  }
}

// ---------------- chunked prefix scan of v ----------------
__global__ __launch_bounds__(256) void scan1_kernel(const unsigned short* __restrict__ qkv,
                                                    float* __restrict__ S) {
  int b = blockIdx.x >> 6, ch = blockIdx.x & 63, c = threadIdx.x;
  float s = 0.f;
  size_t base = ((size_t)b * T_ + (size_t)ch * CHL_) * C3_ + 512 + c;
  for (int t = 0; t < CHL_; t++) s += b2f(qkv[base + (size_t)t * C3_]);
  S[((size_t)b * NCH_ + ch) * C_ + c] = s;
}
__global__ __launch_bounds__(256) void scan2_kernel(float* __restrict__ S) {
  int b = blockIdx.x, c = threadIdx.x;
  float run = 0.f;
  for (int ch = 0; ch < NCH_; ch++) {
    size_t i = ((size_t)b * NCH_ + ch) * C_ + c;
    float t = S[i]; S[i] = run; run += t;
  }
}
__global__ __launch_bounds__(256) void scan3_kernel(const unsigned short* __restrict__ qkv,
                                                    const float* __restrict__ S,
                                                    unsigned short* __restrict__ Pb) {
  int b = blockIdx.x >> 6, ch = blockIdx.x & 63, c = threadIdx.x;
  float run = S[((size_t)b * NCH_ + ch) * C_ + c];
  size_t row0 = (size_t)b * T_ + (size_t)ch * CHL_;
  for (int t = 0; t < CHL_; t++) {
    run += b2f(qkv[(row0 + t) * C3_ + 512 + c]);
    Pb[(row0 + t) * C_ + c] = f2b(run);
  }
}

// ---------------- windowed attention: 16-lane group per window position ----------------
__global__ __launch_bounds__(256) void attn_kernel(
    const unsigned short* __restrict__ qkv, const unsigned short* __restrict__ Pb,
    const float* __restrict__ gate, unsigned short* __restrict__ aout) {
  int wave = threadIdx.x >> 6, lane = threadIdx.x & 63;
  int r = blockIdx.x * 4 + wave;
  int t = r & (T_ - 1);
  int g = lane >> 4, u = lane & 15;
  const unsigned short* qp = qkv + (size_t)r * C3_ + (u << 4);
  float qv[16];
  unpack8(*(const uint4*)qp, qv);
  unpack8(*(const uint4*)(qp + 8), qv + 8);
  float sc[5];
  #pragma unroll
  for (int rnd = 0; rnd < 5; rnd++) {
    int j = rnd * 4 + g;
    int jj = t - 16 + j;
    bool valid = (j <= 16) && (jj >= 0);
    float d = 0.f;
    if (valid) {
      const unsigned short* kp = qkv + (size_t)(r - 16 + j) * C3_ + 256 + (u << 4);
      float kv[16];
      unpack8(*(const uint4*)kp, kv);
      unpack8(*(const uint4*)(kp + 8), kv + 8);
      #pragma unroll
      for (int c = 0; c < 16; c++) d += qv[c] * kv[c];
    }
    d += __shfl_xor(d, 1); d += __shfl_xor(d, 2);
    d += __shfl_xor(d, 4); d += __shfl_xor(d, 8);
    sc[rnd] = valid ? d * 0.0625f : -1e30f;
  }
  float m = fmaxf(fmaxf(fmaxf(sc[0], sc[1]), fmaxf(sc[2], sc[3])), sc[4]);
  m = fmaxf(m, __shfl_xor(m, 16));
  m = fmaxf(m, __shfl_xor(m, 32));
  if (t > 16) m = fmaxf(m, 0.0f);
  float ev[5], Zp = 0.f;
  #pragma unroll
  for (int rnd = 0; rnd < 5; rnd++) {
    ev[rnd] = (sc[rnd] > -1e29f) ? __expf(sc[rnd] - m) : 0.f;
    Zp += ev[rnd];
  }
  Zp += __shfl_xor(Zp, 16);
  Zp += __shfl_xor(Zp, 32);
  float e0v = 0.f;
  if (t > 16) { e0v = __expf(-m); Zp += e0v * (float)(t - 16); }
  float vp[16];
  #pragma unroll
  for (int c = 0; c < 16; c++) vp[c] = 0.f;
  #pragma unroll
  for (int rnd = 0; rnd < 5; rnd++) {
    if (ev[rnd] != 0.f) {
      int j = rnd * 4 + g;
      const unsigned short* vpp = qkv + (size_t)(r - 16 + j) * C3_ + 512 + (u << 4);
      float vv[16];
      unpack8(*(const uint4*)vpp, vv);
      unpack8(*(const uint4*)(vpp + 8), vv + 8);
      #pragma unroll
      for (int c = 0; c < 16; c++) vp[c] += ev[rnd] * vv[c];
    }
  }
  #pragma unroll
  for (int c = 0; c < 16; c++) {
    vp[c] += __shfl_xor(vp[c], 16);
    vp[c] += __shfl_xor(vp[c], 32);
  }
  if (g == 0) {
    if (t > 16) {
      const unsigned short* pp = Pb + (size_t)(r - 17) * C_ + (u << 4);
      float pv[16];
      unpack8(*(const uint4*)pp, pv);
      unpack8(*(const uint4*)(pp + 8), pv + 8);
      #pragma unroll
      for (int c = 0; c < 16; c++) vp[c] += e0v * pv[c];
    }
    float inv = 1.0f / Zp;
    const float* gp = gate + (u << 4);
    unsigned int ow[8];
    #pragma unroll
    for (int i = 0; i < 8; i++) {
      unsigned short lo = f2b(vp[2*i] * inv * gp[2*i]);
      unsigned short hi = f2b(vp[2*i+1] * inv * gp[2*i+1]);
      ow[i] = (unsigned int)lo | ((unsigned int)hi << 16);
    }
    uint4 s0 = {ow[0], ow[1], ow[2], ow[3]};
    uint4 s1 = {ow[4], ow[5], ow[6], ow[7]};
    *(uint4*)(aout + (size_t)r * C_ + (u << 4)) = s0;
    *(uint4*)(aout + (size_t)r * C_ + (u << 4) + 8) = s1;
  }
}

// ---------------- 128x128 MFMA GEMM, operand-swapped, swizzled staging ------------------
// EPI 0: outb = bf16(acc + bias)                              (qkv)
// EPI 1: x1 = acc + bias + resid                              (proj)
template<int EPI>
__global__ __launch_bounds__(256) void gemm128(
    const unsigned short* __restrict__ A, const unsigned short* __restrict__ Bt,
    const float* __restrict__ bias, int K, int ldOut,
    const float* __restrict__ resid, float* __restrict__ outf,
    unsigned short* __restrict__ outb) {
  __shared__ __align__(16) unsigned short As[128 * 64];
  __shared__ __align__(16) unsigned short Bs[128 * 64];
  const int tid = threadIdx.x;
  const int wave = tid >> 6, lane = tid & 63;
  const int mBlk = blockIdx.x * 128, nBlk = blockIdx.y * 128;
  const int wm = (wave >> 1) * 64, wn = (wave & 1) * 64;
  const int lm = lane & 15, lk = (lane >> 4) * 8;
  floatx4 acc[4][4];
  #pragma unroll
  for (int i = 0; i < 4; i++)
    #pragma unroll
    for (int j = 0; j < 4; j++) acc[i][j] = (floatx4){0.f, 0.f, 0.f, 0.f};

  for (int kt = 0; kt < K; kt += 64) {
    __syncthreads();
    #pragma unroll
    for (int i = 0; i < 4; i++) {
      int seg = i * 256 + tid;          // 16B segment index
      int row = seg >> 3, g = seg & 7;
      int gc = (g ^ (row & 7)) << 3;    // XOR-swizzle the GLOBAL column (LDS stays linear)
      gl_lds16(A + (size_t)(mBlk + row) * K + kt + gc, &As[seg * 8]);
      gl_lds16(Bt + (size_t)(nBlk + row) * K + kt + gc, &Bs[seg * 8]);
    }
    __syncthreads();
    #pragma unroll
    for (int kk = 0; kk < 64; kk += 32) {
      short8 mf[4], nf[4];
      #pragma unroll
      for (int j = 0; j < 4; j++) {
        int row = wm + j * 16 + lm;
        mf[j] = *(const short8*)&As[row * 64 + ((((kk + lk) >> 3) ^ (row & 7)) << 3)];
      }
      #pragma unroll
      for (int i = 0; i < 4; i++) {
        int row = wn + i * 16 + lm;
        nf[i] = *(const short8*)&Bs[row * 64 + ((((kk + lk) >> 3) ^ (row & 7)) << 3)];
      }
      #pragma unroll
      for (int i = 0; i < 4; i++)
        #pragma unroll
        for (int j = 0; j < 4; j++)
          acc[i][j] = __builtin_amdgcn_mfma_f32_16x16x32_bf16(nf[i], mf[j], acc[i][j], 0, 0, 0);
    }
  }
  const int lc = lane & 15, quad = lane >> 4, q4 = quad * 4;
  #pragma unroll
  for (int i = 0; i < 4; i++) {
    int n0 = nBlk + wn + i * 16 + q4;
    float4 bs = *(const float4*)&bias[n0];
    #pragma unroll
    for (int j = 0; j < 4; j++) {
      int m = mBlk + wm + j * 16 + lc;
      float v0 = acc[i][j][0] + bs.x, v1 = acc[i][j][1] + bs.y;
      float v2 = acc[i][j][2] + bs.z, v3 = acc[i][j][3] + bs.w;
      if (EPI == 0) {
        ushort4 o = {f2b(v0), f2b(v1), f2b(v2), f2b(v3)};
        *(ushort4*)&outb[(size_t)m * ldOut + n0] = o;
      } else {
        size_t idx = (size_t)m * ldOut + n0;
        float4 r = *(const float4*)&resid[idx];
        float4 o = {v0 + r.x, v1 + r.y, v2 + r.z, v3 + r.w};
        *(float4*)&outf[idx] = o;
      }
    }
  }
}

// ---------------- fused MoE, producer/consumer split + counted-vmcnt deep prefetch ------
// R7 structure (8 waves: 4 up 32m x 32h, 4 down 64m x 64c; 64-row blocks; 64 chunks),
// with the stage pipeline deepened per T4: W1/b1 staged 2 chunks ahead (triple buffer),
// W2 staged 1 ahead (triple buffer -> no same-iter write/read hazard), Hs dbuf.
// Per iter: barrier -> stageW2(c+1 -> (c+1)%3) -> stageW1(c+2 -> (c+2)%3) -> compute(c)
//           -> vmcnt(5).
// vmcnt(5): the 5 newest outstanding loads are W1(c+2)'s; everything older — W2(c+1)
// [issued this iter, before W1] and W1(c+1) [issued last iter] — is landed before any
// wave reaches the next barrier.  So chunk-c data is globally visible at iter c's top
// barrier while W1(c+2) stays in flight ACROSS it: the per-iter DMA drain (R7's
// vmcnt(0), the suspected ~30-50% stall) disappears.
// Rotation audit: W1 write (c+2)%3 / read c%3 (last read of the overwritten buf was
// chunk c-1, finished pre-barrier).  W2 write (c+1)%3 / read (c-1)%3 (distinct; buf
// re-written 2 iters after its last read).  B1s follows W1.  Hs unchanged from R7.
// LDS 152.8 KB -> 1 block/CU (same occupancy as R7).
__global__ __launch_bounds__(512, 2) void moe_fused(
    const unsigned short* __restrict__ h2,   // [M,256] bf16
    const unsigned short* __restrict__ w1t,  // [4096,256] bf16
    const float* __restrict__ b1,            // [4096] flat
    const unsigned char* __restrict__ w2b,   // [64][256][64] fp8 (x256, seg-swizzled)
    const float* __restrict__ b2,            // [4][256]
    const float* __restrict__ gates,         // [M,4]
    const float* __restrict__ x1,            // [M,256]
    float* __restrict__ out) {
  __shared__ __align__(16) unsigned short W1s[3][64 * 256];    // 96 KB
  __shared__ __align__(16) unsigned char  W2s[3][256 * 64];    // 48 KB
  __shared__ __align__(16) unsigned char  Hs[2][64 * 64];      // 8 KB
  __shared__ __align__(16) float          B1s[3][64];          // 768 B
  const int tid = threadIdx.x;
  const int wave = tid >> 6, lane = tid & 63;
  const int lm = lane & 15, quad = lane >> 4;
  const int mb = blockIdx.x * 64;
  const bool isUp = wave < 4;
  const int uw = wave & 3;
  const int wmu = (uw >> 1) * 32;     // up-tile m offset
  const int whu = (uw & 1) * 32;      // up-tile h offset
  const int wc  = uw * 64;            // down-tile c offset

  // stage W1 chunk c + b1 slice into buffer buf: 5 vmem instrs/wave
  auto stageW1 = [&](int c, int buf) {
    const unsigned short* ws = w1t + (size_t)c * 64 * C_;
    #pragma unroll
    for (int t = 0; t < 4; t++) {
      int seg = t * 512 + tid;
      int row = seg >> 5, g = seg & 31;
      int gp = (g & 24) | ((g & 7) ^ (row & 7));
      gl_lds16(ws + (size_t)row * C_ + gp * 8, &W1s[buf][seg * 8]);
    }
    if (lane < 16)
      gl_lds16(b1 + (size_t)c * 64 + lane * 4, &B1s[buf][0]);
  };
  // stage W2 chunk c into buffer buf: 2 vmem instrs/wave (pre-blocked linear 16 KB)
  auto stageW2 = [&](int c, int buf) {
    const unsigned char* vs = w2b + (size_t)c * 256 * 64;
    #pragma unroll
    for (int t = 0; t < 2; t++) {
      int seg = t * 512 + tid;
      gl_lds16(vs + (size_t)seg * 16, &W2s[buf][seg * 16]);
    }
  };

  // prologue: chunks 0,1 of W1/b1; chunk 0 of W2
  stageW1(0, 0);
  stageW1(1, 1);
  stageW2(0, 0);

  // A-fragments -> registers (up waves): h2 rows [mb+wmu, +32), read once, reused 64 chunks
  short8 af[8][2];
  float4 ga[2];
  if (isUp) {
    #pragma unroll
    for (int kk = 0; kk < 8; kk++) {
      int kc = kk * 4 + quad;
      #pragma unroll
      for (int j = 0; j < 2; j++) {
        int row = mb + wmu + j * 16 + lm;
        af[kk][j] = *(const short8*)(h2 + (size_t)row * C_ + kc * 8);
      }
    }
    #pragma unroll
    for (int j = 0; j < 2; j++)
      ga[j] = *(const float4*)(gates + (size_t)(mb + wmu + j * 16 + lm) * 4);
  }

  floatx4 dacc[4][4];   // [i = c-frag][j = m-frag], down waves only
  #pragma unroll
  for (int i = 0; i < 4; i++)
    #pragma unroll
    for (int j = 0; j < 4; j++) dacc[i][j] = (floatx4){0.f, 0.f, 0.f, 0.f};

  // prologue drain: chunks 0/1 staged + af/ga landed before first barrier
  asm volatile("s_waitcnt vmcnt(0)" ::: "memory");

  for (int c = 0; c < 64; c++) {
    const int wb = c % 3;              // W1/B1 buffer for chunk c
    const int hb = c & 1;              // Hs buffer for chunk c
    // top barrier: all waves' chunk-c (and older) stages landed (their vmcnt(5) before
    // arrival left only W1(c+1)'s loads in flight) and compute(c-1) finished everywhere
    __builtin_amdgcn_s_barrier();
    __builtin_amdgcn_sched_barrier(0);
    stageW2((c + 1) & 63, (c + 1) % 3);   // W2 for chunk c+1 (consumed at iter c+2)
    stageW1((c + 2) & 63, (c + 2) % 3);   // W1/b1 for chunk c+2 (consumed at iter c+2)

    if (isUp) {
      // ---- up-GEMM chunk c: uacc = h2[32m] x w1[32h], K=256
      floatx4 uacc[2][2];
      #pragma unroll
      for (int i = 0; i < 2; i++)
        #pragma unroll
        for (int j = 0; j < 2; j++) uacc[i][j] = (floatx4){0.f, 0.f, 0.f, 0.f};
      __builtin_amdgcn_s_setprio(1);
      #pragma unroll
      for (int kk = 0; kk < 8; kk++) {
        int kc = kk * 4 + quad;
        short8 nf[2];
        #pragma unroll
        for (int i = 0; i < 2; i++) {
          int row = whu + i * 16 + lm;
          nf[i] = *(const short8*)&W1s[wb][row * 256 + ((kc ^ (row & 7)) << 3)];
        }
        #pragma unroll
        for (int i = 0; i < 2; i++)
          #pragma unroll
          for (int j = 0; j < 2; j++)
            uacc[i][j] = __builtin_amdgcn_mfma_f32_16x16x32_bf16(nf[i], af[kk][j], uacc[i][j], 0, 0, 0);
      }
      __builtin_amdgcn_s_setprio(0);
      // ---- gelu + gate + fp8 -> Hs[hb], XOR-swizzled 8B granules
      int e = c >> 4;
      float gs0 = 64.0f * sel4(ga[0], e);
      float gs1 = 64.0f * sel4(ga[1], e);
      #pragma unroll
      for (int i = 0; i < 2; i++) {
        float4 bb = *(const float4*)&B1s[wb][whu + i * 16 + quad * 4];
        #pragma unroll
        for (int j = 0; j < 2; j++) {
          float gs = j ? gs1 : gs0;
          unsigned int w = pk_fp8x4(gs * gelu_s(uacc[i][j][0] + bb.x),
                                    gs * gelu_s(uacc[i][j][1] + bb.y),
                                    gs * gelu_s(uacc[i][j][2] + bb.z),
                                    gs * gelu_s(uacc[i][j][3] + bb.w));
          int m = wmu + j * 16 + lm;
          int hh = whu + i * 16 + quad * 4;
          *(unsigned int*)&Hs[hb][m * 64 + ((((hh >> 3) ^ (m & 7)) << 3) | (hh & 7))] = w;
        }
      }
      asm volatile("s_waitcnt lgkmcnt(0)" ::: "memory");   // Hs writes landed before barrier
    } else if (c > 0) {
      // ---- down-GEMM chunk c-1: dacc += hid8[64m x 64k] x w2[64c x 64k] (fp8)
      const int pb = hb ^ 1;            // Hs buffer of chunk c-1
      const int vb = (c - 1) % 3;       // W2 buffer of chunk c-1
      __builtin_amdgcn_s_setprio(1);
      #pragma unroll
      for (int kk = 0; kk < 2; kk++) {
        long mfh[4], nfw[4];
        #pragma unroll
        for (int j = 0; j < 4; j++) {
          int m = j * 16 + lm;
          int g8 = quad + 4 * kk;
          mfh[j] = *(const long*)&Hs[pb][m * 64 + ((g8 ^ (m & 7)) << 3)];
        }
        #pragma unroll
        for (int i = 0; i < 4; i++) {
          int cr = wc + i * 16 + lm;
          int sl = ((quad >> 1) + 2 * kk) ^ ((cr >> 2) & 3);
          nfw[i] = *(const long*)&W2s[vb][cr * 64 + (sl << 4) + ((quad & 1) << 3)];
        }
        #pragma unroll
        for (int i = 0; i < 4; i++)
          #pragma unroll
          for (int j = 0; j < 4; j++)
            dacc[i][j] = __builtin_amdgcn_mfma_f32_16x16x32_fp8_fp8(nfw[i], mfh[j], dacc[i][j], 0, 0, 0);
      }
      __builtin_amdgcn_s_setprio(0);
    }
    // counted drain: leave only this iter's W1(c+2) 5 loads in flight; W2(c+1) and
    // W1(c+1) (older) are complete before announcing arrival at the next barrier
    asm volatile("s_waitcnt vmcnt(5)" ::: "memory");
  }

  // ---- drain: final down step for chunk 63 (Hs[1], W2s[63%3=0]), then epilogue
  asm volatile("s_waitcnt vmcnt(0)" ::: "memory");
  __builtin_amdgcn_s_barrier();
  __builtin_amdgcn_sched_barrier(0);
  if (!isUp) {
    const int vb = 63 % 3;
    #pragma unroll
    for (int kk = 0; kk < 2; kk++) {
      long mfh[4], nfw[4];
      #pragma unroll
      for (int j = 0; j < 4; j++) {
        int m = j * 16 + lm;
        int g8 = quad + 4 * kk;
        mfh[j] = *(const long*)&Hs[1][m * 64 + ((g8 ^ (m & 7)) << 3)];
      }
      #pragma unroll
      for (int i = 0; i < 4; i++) {
        int cr = wc + i * 16 + lm;
        int sl = ((quad >> 1) + 2 * kk) ^ ((cr >> 2) & 3);
        nfw[i] = *(const long*)&W2s[vb][cr * 64 + (sl << 4) + ((quad & 1) << 3)];
      }
      #pragma unroll
      for (int i = 0; i < 4; i++)
        #pragma unroll
        for (int j = 0; j < 4; j++)
          dacc[i][j] = __builtin_amdgcn_mfma_f32_16x16x32_fp8_fp8(nfw[i], mfh[j], dacc[i][j], 0, 0, 0);
    }
    // ---- epilogue: out = dacc/2^14 + x1 + sum_e gate_e * b2_e
    const float sc = 1.0f / 16384.0f;
    const int q4 = quad * 4;
    #pragma unroll
    for (int j = 0; j < 4; j++) {
      int m = mb + j * 16 + lm;
      float4 g4 = *(const float4*)(gates + (size_t)m * 4);
      #pragma unroll
      for (int i = 0; i < 4; i++) {
        int n0 = wc + i * 16 + q4;
        float4 bA = *(const float4*)&b2[0 * C_ + n0];
        float4 bB = *(const float4*)&b2[1 * C_ + n0];
        float4 bC = *(const float4*)&b2[2 * C_ + n0];
        float4 bD = *(const float4*)&b2[3 * C_ + n0];
        size_t idx = (size_t)m * C_ + n0;
        float4 r = *(const float4*)&x1[idx];
        float4 o;
        o.x = dacc[i][j][0]*sc + r.x + g4.x*bA.x + g4.y*bB.x + g4.z*bC.x + g4.w*bD.x;
        o.y = dacc[i][j][1]*sc + r.y + g4.x*bA.y + g4.y*bB.y + g4.z*bC.y + g4.w*bD.y;
        o.z = dacc[i][j][2]*sc + r.z + g4.x*bA.z + g4.y*bB.z + g4.z*bC.z + g4.w*bD.z;
        o.w = dacc[i][j][3]*sc + r.w + g4.x*bA.w + g4.y*bB.w + g4.z*bC.w + g4.w*bD.w;
        *(float4*)&out[idx] = o;
      }
    }
  }
}

extern "C" void kernel_launch(void* const* d_in, const int* in_sizes, int n_in,
                              void* d_out, int out_size, void* d_ws, size_t ws_size,
                              hipStream_t stream) {
  const float* x       = (const float*)d_in[0];
  const float* ln1_g   = (const float*)d_in[1];
  const float* ln1_b   = (const float*)d_in[2];
  const float* qkv_w   = (const float*)d_in[3];
  const float* qkv_b   = (const float*)d_in[4];
  const float* proj_w  = (const float*)d_in[5];
  const float* proj_b  = (const float*)d_in[6];
  const float* attn_g  = (const float*)d_in[7];
  const float* ln2_g   = (const float*)d_in[8];
  const float* ln2_b   = (const float*)d_in[9];
  const float* gat_w   = (const float*)d_in[10];
  const float* gat_b   = (const float*)d_in[11];
  const float* e_w1    = (const float*)d_in[12];
  const float* e_b1    = (const float*)d_in[13];
  const float* e_w2    = (const float*)d_in[14];
  const float* e_b2    = (const float*)d_in[15];
  float* out = (float*)d_out;

  char* p = (char*)d_ws;
  unsigned short* h    = (unsigned short*)p; p += (size_t)M_ * C_ * 2;      // 8 MB
  unsigned short* qkv  = (unsigned short*)p; p += (size_t)M_ * C3_ * 2;     // 24 MB
  unsigned short* Pb   = (unsigned short*)p; p += (size_t)M_ * C_ * 2;      // 8 MB
  unsigned short* aout = (unsigned short*)p; p += (size_t)M_ * C_ * 2;      // 8 MB
  float*          x1   = (float*)p;          p += (size_t)M_ * C_ * 4;      // 16 MB
  unsigned short* h2   = (unsigned short*)p; p += (size_t)M_ * C_ * 2;      // 8 MB
  float*          gts  = (float*)p;          p += (size_t)M_ * E_ * 4;      // 256 KB
  float*          S    = (float*)p;          p += (size_t)B_ * NCH_ * C_ * 4;
  unsigned short* wq   = (unsigned short*)p; p += (size_t)C3_ * C_ * 2;
  unsigned short* wp   = (unsigned short*)p; p += (size_t)C_ * C_ * 2;
  unsigned short* w1t  = (unsigned short*)p; p += (size_t)KH_ * C_ * 2;     // 2 MB [4096,256]
  unsigned char*  w2f8 = (unsigned char*)p;  p += (size_t)C_ * KH_;         // 1 MB blocked

  dim3 t32x8(32, 8);
  transpose_cvt<<<dim3(C3_/32, C_/32, 1), t32x8, 0, stream>>>(qkv_w, wq, C_, C3_, C_, 0);
  transpose_cvt<<<dim3(C_/32, C_/32, 1),  t32x8, 0, stream>>>(proj_w, wp, C_, C_, C_, 0);
  // w1t[e*1024 + hrow][c]  (flat [4096, 256]) bf16
  transpose_cvt<<<dim3(H_/32, C_/32, E_), t32x8, 0, stream>>>(e_w1, w1t, C_, H_, C_, (size_t)H_ * C_);
  // w2 -> fp8 x256, blocked [64 chunks][c][64] with (c>>2) seg swizzle
  transpose_w2_fp8<<<dim3(H_/32, C_/32, E_), t32x8, 0, stream>>>(e_w2, w2f8);

  ln1_kernel<<<M_, 256, 0, stream>>>(x, ln1_g, ln1_b, h);
  gemm128<0><<<dim3(M_/128, C3_/128), 256, 0, stream>>>(h, wq, qkv_b, C_, C3_,
      nullptr, nullptr, qkv);
  scan1_kernel<<<B_*NCH_, 256, 0, stream>>>(qkv, S);
  scan2_kernel<<<B_, 256, 0, stream>>>(S);
  scan3_kernel<<<B_*NCH_, 256, 0, stream>>>(qkv, S, Pb);
  attn_kernel<<<M_/4, 256, 0, stream>>>(qkv, Pb, attn_g, aout);
  // x1 = x + aout @ proj_w + proj_b
  gemm128<1><<<dim3(M_/128, C_/128), 256, 0, stream>>>(aout, wp, proj_b, C_, C_,
      x, x1, nullptr);
  ln2_gates_kernel<<<M_, 256, 0, stream>>>(x1, ln2_g, ln2_b, gat_w, gat_b, h2, gts);
  // fused MoE: producer/consumer waves, triple-buffered weights, counted vmcnt(5)
  moe_fused<<<M_/64, 512, 0, stream>>>(h2, w1t, e_b1, w2f8, e_b2, gts, x1, out);
}

// Round 12
// 313.910 us; speedup vs baseline: 1.7311x; 1.0177x over previous
//
#include <hip/hip_runtime.h>
#include <hip/hip_bf16.h>
#include <math.h>

#define T_   4096
#define B_   4
#define C_   256
#define C3_  768
#define H_   1024
#define E_   4
#define M_   (B_*T_)      // 16384 rows
#define NCH_ 64
#define CHL_ (T_/NCH_)    // 64
#define KH_  4096         // E*H

typedef __attribute__((ext_vector_type(8))) short short8;
typedef __attribute__((ext_vector_type(4))) float floatx4;

__device__ __forceinline__ float b2f(unsigned short u) {
  union { unsigned int i; float f; } x; x.i = ((unsigned int)u) << 16; return x.f;
}
__device__ __forceinline__ unsigned short f2b(float f) {
  __hip_bfloat16 h = __float2bfloat16(f);
  return *reinterpret_cast<unsigned short*>(&h);
}
__device__ __forceinline__ void unpack8(uint4 a, float* f) {
  unsigned int w[4] = {a.x, a.y, a.z, a.w};
  #pragma unroll
  for (int i = 0; i < 4; i++) {
    union { unsigned int u; float g; } lo, hi;
    lo.u = w[i] << 16; hi.u = w[i] & 0xffff0000u;
    f[2*i] = lo.g; f[2*i+1] = hi.g;
  }
}
__device__ __forceinline__ void gl_lds16(const void* g, void* l) {
  __builtin_amdgcn_global_load_lds(
      (const __attribute__((address_space(1))) void*)g,
      (__attribute__((address_space(3))) void*)l, 16, 0, 0);
}
// sigmoid GELU: x*sigma(1.702x). |err|<=~0.01 on hid; attenuated by zero-mean w2 down-sum.
// Numerics verified on HW: passed with absmax 0.03125 using this form.
__device__ __forceinline__ float gelu_s(float v) {
  float e = __expf(-1.702f * v);
  return v * __builtin_amdgcn_rcpf(1.0f + e);
}
// pack 4 floats -> 4 fp8 e4m3 (OCP) in one uint
__device__ __forceinline__ unsigned int pk_fp8x4(float a, float b, float c, float d) {
  unsigned int v = 0;
  v = __builtin_amdgcn_cvt_pk_fp8_f32(a, b, v, false);
  v = __builtin_amdgcn_cvt_pk_fp8_f32(c, d, v, true);
  return v;
}
__device__ __forceinline__ unsigned char f2fp8(float v) {
  return (unsigned char)(__builtin_amdgcn_cvt_pk_fp8_f32(v, v, 0, false) & 0xff);
}
__device__ __forceinline__ float sel4(float4 v, int e) {
  float r = v.x;
  r = (e == 1) ? v.y : r;
  r = (e == 2) ? v.z : r;
  r = (e == 3) ? v.w : r;
  return r;
}

// ---------------- transpose + fp32->bf16: src[K,N](+z*K*N) -> dst[+z*zStr][n*dstLd + k] ----
__global__ __launch_bounds__(256) void transpose_cvt(
    const float* __restrict__ src, unsigned short* __restrict__ dst, int K, int N,
    int dstLd, size_t dstZStride) {
  __shared__ float tile[32][33];
  src += (size_t)blockIdx.z * K * N;
  dst += (size_t)blockIdx.z * dstZStride;
  int n0 = blockIdx.x * 32, k0 = blockIdx.y * 32;
  int tx = threadIdx.x, ty = threadIdx.y;   // blockDim (32,8)
  #pragma unroll
  for (int i = 0; i < 32; i += 8)
    tile[ty + i][tx] = src[(size_t)(k0 + ty + i) * N + n0 + tx];
  __syncthreads();
  #pragma unroll
  for (int i = 0; i < 32; i += 8)
    dst[(size_t)(n0 + ty + i) * dstLd + k0 + tx] = f2b(tile[tx][ty + i]);
}

// ---------------- w2 -> fp8 blocked: w2b[chunk=k>>6][c][64 bytes, seg-swizzled] ----------
// value = fp8(w2[e][h][c] * 256), k = e*1024+h.  Within the 64-byte row the 16B seg s
// is stored at s ^ ((c>>2)&3): down-GEMM b64 read bank = 16(c&1)+4(s^((c>>2)&3))+2(q&1)
// -> (c&1,(c>>2)&3) takes 8 distinct values over 16 lanes = 2-way (free).
__global__ __launch_bounds__(256) void transpose_w2_fp8(
    const float* __restrict__ src, unsigned char* __restrict__ dst) {
  __shared__ float tile[32][33];
  int e = blockIdx.z;
  src += (size_t)e * H_ * C_;
  int h0 = blockIdx.x * 32, c0 = blockIdx.y * 32;
  int tx = threadIdx.x, ty = threadIdx.y;
  #pragma unroll
  for (int i = 0; i < 32; i += 8)
    tile[ty + i][tx] = src[(size_t)(h0 + ty + i) * C_ + c0 + tx];
  __syncthreads();
  int k = e * H_ + h0 + tx;
  int chunk = k >> 6, kc = k & 63;
  #pragma unroll
  for (int i = 0; i < 32; i += 8) {
    int c = c0 + ty + i;
    int sw = ((((kc >> 4) ^ ((c >> 2) & 3)) << 4) | (kc & 15));
    dst[((size_t)chunk * 256 + c) * 64 + sw] = f2fp8(tile[tx][ty + i] * 256.0f);
  }
}

// ---------------- LayerNorm 1 ----------------
__global__ __launch_bounds__(256) void ln1_kernel(
    const float* __restrict__ x, const float* __restrict__ g,
    const float* __restrict__ b, unsigned short* __restrict__ h) {
  __shared__ float red[4];
  int row = blockIdx.x, tid = threadIdx.x;
  float v = x[(size_t)row * C_ + tid];
  float s = v;
  #pragma unroll
  for (int o = 32; o; o >>= 1) s += __shfl_xor(s, o);
  if ((tid & 63) == 0) red[tid >> 6] = s;
  __syncthreads();
  float mean = (red[0] + red[1] + red[2] + red[3]) * (1.0f / C_);
  __syncthreads();
  float d = v - mean;
  float q = d * d;
  #pragma unroll
  for (int o = 32; o; o >>= 1) q += __shfl_xor(q, o);
  if ((tid & 63) == 0) red[tid >> 6] = q;
  __syncthreads();
  float var = (red[0] + red[1] + red[2] + red[3]) * (1.0f / C_);
  h[(size_t)row * C_ + tid] = f2b(d * rsqrtf(var + 1e-5f) * g[tid] + b[tid]);
}

// ---------------- LayerNorm 2 + gating softmax (h2 bf16) ----------------
__global__ __launch_bounds__(256) void ln2_gates_kernel(
    const float* __restrict__ x1, const float* __restrict__ g,
    const float* __restrict__ b, const float* __restrict__ gw,
    const float* __restrict__ gb, unsigned short* __restrict__ h2,
    float* __restrict__ gates) {
  __shared__ float red[4];
  __shared__ float redg[4][4];
  int row = blockIdx.x, tid = threadIdx.x;
  float v = x1[(size_t)row * C_ + tid];
  float s = v;
  #pragma unroll
  for (int o = 32; o; o >>= 1) s += __shfl_xor(s, o);
  if ((tid & 63) == 0) red[tid >> 6] = s;
  __syncthreads();
  float mean = (red[0] + red[1] + red[2] + red[3]) * (1.0f / C_);
  __syncthreads();
  float d = v - mean;
  float q = d * d;
  #pragma unroll
  for (int o = 32; o; o >>= 1) q += __shfl_xor(q, o);
  if ((tid & 63) == 0) red[tid >> 6] = q;
  __syncthreads();
  float var = (red[0] + red[1] + red[2] + red[3]) * (1.0f / C_);
  float hv = d * rsqrtf(var + 1e-5f) * g[tid] + b[tid];
  h2[(size_t)row * C_ + tid] = f2b(hv);
  float p0 = hv * gw[tid * 4 + 0];
  float p1 = hv * gw[tid * 4 + 1];
  float p2 = hv * gw[tid * 4 + 2];
  float p3 = hv * gw[tid * 4 + 3];
  #pragma unroll
  for (int o = 32; o; o >>= 1) {
    p0 += __shfl_xor(p0, o); p1 += __shfl_xor(p1, o);
    p2 += __shfl_xor(p2, o); p3 += __shfl_xor(p3, o);
  }
  if ((tid & 63) == 0) {
    int w = tid >> 6;
    redg[w][0] = p0; redg[w][1] = p1; redg[w][2] = p2; redg[w][3] = p3;
  }
  __syncthreads();
  if (tid == 0) {
    float t4[4];
    #pragma unroll
    for (int e = 0; e < 4; e++)
      t4[e] = redg[0][e] + redg[1][e] + redg[2][e] + redg[3][e] + gb[e];
    float m = fmaxf(fmaxf(t4[0], t4[1]), fmaxf(t4[2], t4[3]));
    float zs = 0.f;
    #pragma unroll
    for (int e = 0; e < 4; e++) { t4[e] = __expf(t4[e] - m); zs += t4[e]; }
    float inv = 1.0f / zs;
    #pragma unroll
    for (int e = 0; e < 4; e++) gates[(size_t)row * 4 + e] = t4[e] * inv;
  }
}

// ---------------- chunked prefix scan of v ----------------
__global__ __launch_bounds__(256) void scan1_kernel(const unsigned short* __restrict__ qkv,
                                                    float* __restrict__ S) {
  int b = blockIdx.x >> 6, ch = blockIdx.x & 63, c = threadIdx.x;
  float s = 0.f;
  size_t base = ((size_t)b * T_ + (size_t)ch * CHL_) * C3_ + 512 + c;
  for (int t = 0; t < CHL_; t++) s += b2f(qkv[base + (size_t)t * C3_]);
  S[((size_t)b * NCH_ + ch) * C_ + c] = s;
}
__global__ __launch_bounds__(256) void scan2_kernel(float* __restrict__ S) {
  int b = blockIdx.x, c = threadIdx.x;
  float run = 0.f;
  for (int ch = 0; ch < NCH_; ch++) {
    size_t i = ((size_t)b * NCH_ + ch) * C_ + c;
    float t = S[i]; S[i] = run; run += t;
  }
}
__global__ __launch_bounds__(256) void scan3_kernel(const unsigned short* __restrict__ qkv,
                                                    const float* __restrict__ S,
                                                    unsigned short* __restrict__ Pb) {
  int b = blockIdx.x >> 6, ch = blockIdx.x & 63, c = threadIdx.x;
  float run = S[((size_t)b * NCH_ + ch) * C_ + c];
  size_t row0 = (size_t)b * T_ + (size_t)ch * CHL_;
  for (int t = 0; t < CHL_; t++) {
    run += b2f(qkv[(row0 + t) * C3_ + 512 + c]);
    Pb[(row0 + t) * C_ + c] = f2b(run);
  }
}

// ---------------- windowed attention: 16-lane group per window position ----------------
// XCD-aware block swizzle (T1): grid 4096 (4096%8==0 -> bijective). Default round-robin
// puts consecutive blocks on different XCDs, so the 16/17-row K/V overlap between
// neighboring rows never hits the same XCD's L2.  swz=(bid&7)*512+(bid>>3) gives each
// XCD 512 contiguous blocks = 2048 consecutive rows (~3 MB qkv slice, fits 4 MB L2).
__global__ __launch_bounds__(256) void attn_kernel(
    const unsigned short* __restrict__ qkv, const unsigned short* __restrict__ Pb,
    const float* __restrict__ gate, unsigned short* __restrict__ aout) {
  int wave = threadIdx.x >> 6, lane = threadIdx.x & 63;
  int swb = (blockIdx.x & 7) * 512 + (blockIdx.x >> 3);
  int r = swb * 4 + wave;
  int t = r & (T_ - 1);
  int g = lane >> 4, u = lane & 15;
  const unsigned short* qp = qkv + (size_t)r * C3_ + (u << 4);
  float qv[16];
  unpack8(*(const uint4*)qp, qv);
  unpack8(*(const uint4*)(qp + 8), qv + 8);
  float sc[5];
  #pragma unroll
  for (int rnd = 0; rnd < 5; rnd++) {
    int j = rnd * 4 + g;
    int jj = t - 16 + j;
    bool valid = (j <= 16) && (jj >= 0);
    float d = 0.f;
    if (valid) {
      const unsigned short* kp = qkv + (size_t)(r - 16 + j) * C3_ + 256 + (u << 4);
      float kv[16];
      unpack8(*(const uint4*)kp, kv);
      unpack8(*(const uint4*)(kp + 8), kv + 8);
      #pragma unroll
      for (int c = 0; c < 16; c++) d += qv[c] * kv[c];
    }
    d += __shfl_xor(d, 1); d += __shfl_xor(d, 2);
    d += __shfl_xor(d, 4); d += __shfl_xor(d, 8);
    sc[rnd] = valid ? d * 0.0625f : -1e30f;
  }
  float m = fmaxf(fmaxf(fmaxf(sc[0], sc[1]), fmaxf(sc[2], sc[3])), sc[4]);
  m = fmaxf(m, __shfl_xor(m, 16));
  m = fmaxf(m, __shfl_xor(m, 32));
  if (t > 16) m = fmaxf(m, 0.0f);
  float ev[5], Zp = 0.f;
  #pragma unroll
  for (int rnd = 0; rnd < 5; rnd++) {
    ev[rnd] = (sc[rnd] > -1e29f) ? __expf(sc[rnd] - m) : 0.f;
    Zp += ev[rnd];
  }
  Zp += __shfl_xor(Zp, 16);
  Zp += __shfl_xor(Zp, 32);
  float e0v = 0.f;
  if (t > 16) { e0v = __expf(-m); Zp += e0v * (float)(t - 16); }
  float vp[16];
  #pragma unroll
  for (int c = 0; c < 16; c++) vp[c] = 0.f;
  #pragma unroll
  for (int rnd = 0; rnd < 5; rnd++) {
    if (ev[rnd] != 0.f) {
      int j = rnd * 4 + g;
      const unsigned short* vpp = qkv + (size_t)(r - 16 + j) * C3_ + 512 + (u << 4);
      float vv[16];
      unpack8(*(const uint4*)vpp, vv);
      unpack8(*(const uint4*)(vpp + 8), vv + 8);
      #pragma unroll
      for (int c = 0; c < 16; c++) vp[c] += ev[rnd] * vv[c];
    }
  }
  #pragma unroll
  for (int c = 0; c < 16; c++) {
    vp[c] += __shfl_xor(vp[c], 16);
    vp[c] += __shfl_xor(vp[c], 32);
  }
  if (g == 0) {
    if (t > 16) {
      const unsigned short* pp = Pb + (size_t)(r - 17) * C_ + (u << 4);
      float pv[16];
      unpack8(*(const uint4*)pp, pv);
      unpack8(*(const uint4*)(pp + 8), pv + 8);
      #pragma unroll
      for (int c = 0; c < 16; c++) vp[c] += e0v * pv[c];
    }
    float inv = 1.0f / Zp;
    const float* gp = gate + (u << 4);
    unsigned int ow[8];
    #pragma unroll
    for (int i = 0; i < 8; i++) {
      unsigned short lo = f2b(vp[2*i] * inv * gp[2*i]);
      unsigned short hi = f2b(vp[2*i+1] * inv * gp[2*i+1]);
      ow[i] = (unsigned int)lo | ((unsigned int)hi << 16);
    }
    uint4 s0 = {ow[0], ow[1], ow[2], ow[3]};
    uint4 s1 = {ow[4], ow[5], ow[6], ow[7]};
    *(uint4*)(aout + (size_t)r * C_ + (u << 4)) = s0;
    *(uint4*)(aout + (size_t)r * C_ + (u << 4) + 8) = s1;
  }
}

// ---------------- 128x128 MFMA GEMM, operand-swapped, swizzled staging ------------------
// EPI 0: outb = bf16(acc + bias)                              (qkv)
// EPI 1: x1 = acc + bias + resid                              (proj)
template<int EPI>
__global__ __launch_bounds__(256) void gemm128(
    const unsigned short* __restrict__ A, const unsigned short* __restrict__ Bt,
    const float* __restrict__ bias, int K, int ldOut,
    const float* __restrict__ resid, float* __restrict__ outf,
    unsigned short* __restrict__ outb) {
  __shared__ __align__(16) unsigned short As[128 * 64];
  __shared__ __align__(16) unsigned short Bs[128 * 64];
  const int tid = threadIdx.x;
  const int wave = tid >> 6, lane = tid & 63;
  const int mBlk = blockIdx.x * 128, nBlk = blockIdx.y * 128;
  const int wm = (wave >> 1) * 64, wn = (wave & 1) * 64;
  const int lm = lane & 15, lk = (lane >> 4) * 8;
  floatx4 acc[4][4];
  #pragma unroll
  for (int i = 0; i < 4; i++)
    #pragma unroll
    for (int j = 0; j < 4; j++) acc[i][j] = (floatx4){0.f, 0.f, 0.f, 0.f};

  for (int kt = 0; kt < K; kt += 64) {
    __syncthreads();
    #pragma unroll
    for (int i = 0; i < 4; i++) {
      int seg = i * 256 + tid;          // 16B segment index
      int row = seg >> 3, g = seg & 7;
      int gc = (g ^ (row & 7)) << 3;    // XOR-swizzle the GLOBAL column (LDS stays linear)
      gl_lds16(A + (size_t)(mBlk + row) * K + kt + gc, &As[seg * 8]);
      gl_lds16(Bt + (size_t)(nBlk + row) * K + kt + gc, &Bs[seg * 8]);
    }
    __syncthreads();
    #pragma unroll
    for (int kk = 0; kk < 64; kk += 32) {
      short8 mf[4], nf[4];
      #pragma unroll
      for (int j = 0; j < 4; j++) {
        int row = wm + j * 16 + lm;
        mf[j] = *(const short8*)&As[row * 64 + ((((kk + lk) >> 3) ^ (row & 7)) << 3)];
      }
      #pragma unroll
      for (int i = 0; i < 4; i++) {
        int row = wn + i * 16 + lm;
        nf[i] = *(const short8*)&Bs[row * 64 + ((((kk + lk) >> 3) ^ (row & 7)) << 3)];
      }
      #pragma unroll
      for (int i = 0; i < 4; i++)
        #pragma unroll
        for (int j = 0; j < 4; j++)
          acc[i][j] = __builtin_amdgcn_mfma_f32_16x16x32_bf16(nf[i], mf[j], acc[i][j], 0, 0, 0);
    }
  }
  const int lc = lane & 15, quad = lane >> 4, q4 = quad * 4;
  #pragma unroll
  for (int i = 0; i < 4; i++) {
    int n0 = nBlk + wn + i * 16 + q4;
    float4 bs = *(const float4*)&bias[n0];
    #pragma unroll
    for (int j = 0; j < 4; j++) {
      int m = mBlk + wm + j * 16 + lc;
      float v0 = acc[i][j][0] + bs.x, v1 = acc[i][j][1] + bs.y;
      float v2 = acc[i][j][2] + bs.z, v3 = acc[i][j][3] + bs.w;
      if (EPI == 0) {
        ushort4 o = {f2b(v0), f2b(v1), f2b(v2), f2b(v3)};
        *(ushort4*)&outb[(size_t)m * ldOut + n0] = o;
      } else {
        size_t idx = (size_t)m * ldOut + n0;
        float4 r = *(const float4*)&resid[idx];
        float4 o = {v0 + r.x, v1 + r.y, v2 + r.z, v3 + r.w};
        *(float4*)&outf[idx] = o;
      }
    }
  }
}

// ---------------- fused MoE, producer/consumer wave split, 1 barrier/iter (R7 champion) --
// 512 threads: waves 0-3 = up (h2@w1 + gelu + fp8 -> Hs), waves 4-7 = down (Hs@w2 -> dacc).
// Down lags up by one chunk (Hs double-buffered).
// Per iter: barrier -> stage-issue(c+1) -> compute(c) -> vmcnt(0).
__global__ __launch_bounds__(512, 2) void moe_fused(
    const unsigned short* __restrict__ h2,   // [M,256] bf16
    const unsigned short* __restrict__ w1t,  // [4096,256] bf16
    const float* __restrict__ b1,            // [4096] flat
    const unsigned char* __restrict__ w2b,   // [64][256][64] fp8 (x256, seg-swizzled)
    const float* __restrict__ b2,            // [4][256]
    const float* __restrict__ gates,         // [M,4]
    const float* __restrict__ x1,            // [M,256]
    float* __restrict__ out) {
  __shared__ __align__(16) unsigned short W1s[2][64 * 256];    // 64 KB
  __shared__ __align__(16) unsigned char  W2s[2][256 * 64];    // 32 KB
  __shared__ __align__(16) unsigned char  Hs[2][64 * 64];      // 8 KB
  __shared__ __align__(16) float          B1s[2][64];          // 512 B
  const int tid = threadIdx.x;
  const int wave = tid >> 6, lane = tid & 63;
  const int lm = lane & 15, quad = lane >> 4;
  const int mb = blockIdx.x * 64;
  const bool isUp = wave < 4;
  const int uw = wave & 3;
  const int wmu = (uw >> 1) * 32;     // up-tile m offset
  const int whu = (uw & 1) * 32;      // up-tile h offset
  const int wc  = uw * 64;            // down-tile c offset

  auto stageW1 = [&](int c, int buf) {
    const unsigned short* ws = w1t + (size_t)c * 64 * C_;
    #pragma unroll
    for (int t = 0; t < 4; t++) {
      int seg = t * 512 + tid;
      int row = seg >> 5, g = seg & 31;
      int gp = (g & 24) | ((g & 7) ^ (row & 7));
      gl_lds16(ws + (size_t)row * C_ + gp * 8, &W1s[buf][seg * 8]);
    }
    if (lane < 16)
      gl_lds16(b1 + (size_t)c * 64 + lane * 4, &B1s[buf][0]);
  };
  auto stageW2 = [&](int c, int buf) {
    const unsigned char* vs = w2b + (size_t)c * 256 * 64;
    #pragma unroll
    for (int t = 0; t < 2; t++) {
      int seg = t * 512 + tid;
      gl_lds16(vs + (size_t)seg * 16, &W2s[buf][seg * 16]);
    }
  };

  stageW1(0, 0);

  short8 af[8][2];
  float4 ga[2];
  if (isUp) {
    #pragma unroll
    for (int kk = 0; kk < 8; kk++) {
      int kc = kk * 4 + quad;
      #pragma unroll
      for (int j = 0; j < 2; j++) {
        int row = mb + wmu + j * 16 + lm;
        af[kk][j] = *(const short8*)(h2 + (size_t)row * C_ + kc * 8);
      }
    }
    #pragma unroll
    for (int j = 0; j < 2; j++)
      ga[j] = *(const float4*)(gates + (size_t)(mb + wmu + j * 16 + lm) * 4);
  }

  floatx4 dacc[4][4];
  #pragma unroll
  for (int i = 0; i < 4; i++)
    #pragma unroll
    for (int j = 0; j < 4; j++) dacc[i][j] = (floatx4){0.f, 0.f, 0.f, 0.f};

  asm volatile("s_waitcnt vmcnt(0)" ::: "memory");

  for (int c = 0; c < 64; c++) {
    const int wb = c & 1;
    __builtin_amdgcn_s_barrier();
    __builtin_amdgcn_sched_barrier(0);
    stageW1((c + 1) & 63, wb ^ 1);
    stageW2(c, wb);

    if (isUp) {
      floatx4 uacc[2][2];
      #pragma unroll
      for (int i = 0; i < 2; i++)
        #pragma unroll
        for (int j = 0; j < 2; j++) uacc[i][j] = (floatx4){0.f, 0.f, 0.f, 0.f};
      __builtin_amdgcn_s_setprio(1);
      #pragma unroll
      for (int kk = 0; kk < 8; kk++) {
        int kc = kk * 4 + quad;
        short8 nf[2];
        #pragma unroll
        for (int i = 0; i < 2; i++) {
          int row = whu + i * 16 + lm;
          nf[i] = *(const short8*)&W1s[wb][row * 256 + ((kc ^ (row & 7)) << 3)];
        }
        #pragma unroll
        for (int i = 0; i < 2; i++)
          #pragma unroll
          for (int j = 0; j < 2; j++)
            uacc[i][j] = __builtin_amdgcn_mfma_f32_16x16x32_bf16(nf[i], af[kk][j], uacc[i][j], 0, 0, 0);
      }
      __builtin_amdgcn_s_setprio(0);
      int e = c >> 4;
      float gs0 = 64.0f * sel4(ga[0], e);
      float gs1 = 64.0f * sel4(ga[1], e);
      #pragma unroll
      for (int i = 0; i < 2; i++) {
        float4 bb = *(const float4*)&B1s[wb][whu + i * 16 + quad * 4];
        #pragma unroll
        for (int j = 0; j < 2; j++) {
          float gs = j ? gs1 : gs0;
          unsigned int w = pk_fp8x4(gs * gelu_s(uacc[i][j][0] + bb.x),
                                    gs * gelu_s(uacc[i][j][1] + bb.y),
                                    gs * gelu_s(uacc[i][j][2] + bb.z),
                                    gs * gelu_s(uacc[i][j][3] + bb.w));
          int m = wmu + j * 16 + lm;
          int hh = whu + i * 16 + quad * 4;
          *(unsigned int*)&Hs[wb][m * 64 + ((((hh >> 3) ^ (m & 7)) << 3) | (hh & 7))] = w;
        }
      }
      asm volatile("s_waitcnt lgkmcnt(0)" ::: "memory");
    } else if (c > 0) {
      const int pb = wb ^ 1;
      __builtin_amdgcn_s_setprio(1);
      #pragma unroll
      for (int kk = 0; kk < 2; kk++) {
        long mfh[4], nfw[4];
        #pragma unroll
        for (int j = 0; j < 4; j++) {
          int m = j * 16 + lm;
          int g8 = quad + 4 * kk;
          mfh[j] = *(const long*)&Hs[pb][m * 64 + ((g8 ^ (m & 7)) << 3)];
        }
        #pragma unroll
        for (int i = 0; i < 4; i++) {
          int cr = wc + i * 16 + lm;
          int sl = ((quad >> 1) + 2 * kk) ^ ((cr >> 2) & 3);
          nfw[i] = *(const long*)&W2s[pb][cr * 64 + (sl << 4) + ((quad & 1) << 3)];
        }
        #pragma unroll
        for (int i = 0; i < 4; i++)
          #pragma unroll
          for (int j = 0; j < 4; j++)
            dacc[i][j] = __builtin_amdgcn_mfma_f32_16x16x32_fp8_fp8(nfw[i], mfh[j], dacc[i][j], 0, 0, 0);
      }
      __builtin_amdgcn_s_setprio(0);
    }
    asm volatile("s_waitcnt vmcnt(0)" ::: "memory");
  }

  __builtin_amdgcn_s_barrier();
  __builtin_amdgcn_sched_barrier(0);
  if (!isUp) {
    #pragma unroll
    for (int kk = 0; kk < 2; kk++) {
      long mfh[4], nfw[4];
      #pragma unroll
      for (int j = 0; j < 4; j++) {
        int m = j * 16 + lm;
        int g8 = quad + 4 * kk;
        mfh[j] = *(const long*)&Hs[1][m * 64 + ((g8 ^ (m & 7)) << 3)];
      }
      #pragma unroll
      for (int i = 0; i < 4; i++) {
        int cr = wc + i * 16 + lm;
        int sl = ((quad >> 1) + 2 * kk) ^ ((cr >> 2) & 3);
        nfw[i] = *(const long*)&W2s[1][cr * 64 + (sl << 4) + ((quad & 1) << 3)];
      }
      #pragma unroll
      for (int i = 0; i < 4; i++)
        #pragma unroll
        for (int j = 0; j < 4; j++)
          dacc[i][j] = __builtin_amdgcn_mfma_f32_16x16x32_fp8_fp8(nfw[i], mfh[j], dacc[i][j], 0, 0, 0);
    }
    const float sc = 1.0f / 16384.0f;
    const int q4 = quad * 4;
    #pragma unroll
    for (int j = 0; j < 4; j++) {
      int m = mb + j * 16 + lm;
      float4 g4 = *(const float4*)(gates + (size_t)m * 4);
      #pragma unroll
      for (int i = 0; i < 4; i++) {
        int n0 = wc + i * 16 + q4;
        float4 bA = *(const float4*)&b2[0 * C_ + n0];
        float4 bB = *(const float4*)&b2[1 * C_ + n0];
        float4 bC = *(const float4*)&b2[2 * C_ + n0];
        float4 bD = *(const float4*)&b2[3 * C_ + n0];
        size_t idx = (size_t)m * C_ + n0;
        float4 r = *(const float4*)&x1[idx];
        float4 o;
        o.x = dacc[i][j][0]*sc + r.x + g4.x*bA.x + g4.y*bB.x + g4.z*bC.x + g4.w*bD.x;
        o.y = dacc[i][j][1]*sc + r.y + g4.x*bA.y + g4.y*bB.y + g4.z*bC.y + g4.w*bD.y;
        o.z = dacc[i][j][2]*sc + r.z + g4.x*bA.z + g4.y*bB.z + g4.z*bC.z + g4.w*bD.z;
        o.w = dacc[i][j][3]*sc + r.w + g4.x*bA.w + g4.y*bB.w + g4.z*bC.w + g4.w*bD.w;
        *(float4*)&out[idx] = o;
      }
    }
  }
}

extern "C" void kernel_launch(void* const* d_in, const int* in_sizes, int n_in,
                              void* d_out, int out_size, void* d_ws, size_t ws_size,
                              hipStream_t stream) {
  const float* x       = (const float*)d_in[0];
  const float* ln1_g   = (const float*)d_in[1];
  const float* ln1_b   = (const float*)d_in[2];
  const float* qkv_w   = (const float*)d_in[3];
  const float* qkv_b   = (const float*)d_in[4];
  const float* proj_w  = (const float*)d_in[5];
  const float* proj_b  = (const float*)d_in[6];
  const float* attn_g  = (const float*)d_in[7];
  const float* ln2_g   = (const float*)d_in[8];
  const float* ln2_b   = (const float*)d_in[9];
  const float* gat_w   = (const float*)d_in[10];
  const float* gat_b   = (const float*)d_in[11];
  const float* e_w1    = (const float*)d_in[12];
  const float* e_b1    = (const float*)d_in[13];
  const float* e_w2    = (const float*)d_in[14];
  const float* e_b2    = (const float*)d_in[15];
  float* out = (float*)d_out;

  char* p = (char*)d_ws;
  unsigned short* h    = (unsigned short*)p; p += (size_t)M_ * C_ * 2;      // 8 MB
  unsigned short* qkv  = (unsigned short*)p; p += (size_t)M_ * C3_ * 2;     // 24 MB
  unsigned short* Pb   = (unsigned short*)p; p += (size_t)M_ * C_ * 2;      // 8 MB
  unsigned short* aout = (unsigned short*)p; p += (size_t)M_ * C_ * 2;      // 8 MB
  float*          x1   = (float*)p;          p += (size_t)M_ * C_ * 4;      // 16 MB
  unsigned short* h2   = (unsigned short*)p; p += (size_t)M_ * C_ * 2;      // 8 MB
  float*          gts  = (float*)p;          p += (size_t)M_ * E_ * 4;      // 256 KB
  float*          S    = (float*)p;          p += (size_t)B_ * NCH_ * C_ * 4;
  unsigned short* wq   = (unsigned short*)p; p += (size_t)C3_ * C_ * 2;
  unsigned short* wp   = (unsigned short*)p; p += (size_t)C_ * C_ * 2;
  unsigned short* w1t  = (unsigned short*)p; p += (size_t)KH_ * C_ * 2;     // 2 MB [4096,256]
  unsigned char*  w2f8 = (unsigned char*)p;  p += (size_t)C_ * KH_;         // 1 MB blocked

  dim3 t32x8(32, 8);
  transpose_cvt<<<dim3(C3_/32, C_/32, 1), t32x8, 0, stream>>>(qkv_w, wq, C_, C3_, C_, 0);
  transpose_cvt<<<dim3(C_/32, C_/32, 1),  t32x8, 0, stream>>>(proj_w, wp, C_, C_, C_, 0);
  // w1t[e*1024 + hrow][c]  (flat [4096, 256]) bf16
  transpose_cvt<<<dim3(H_/32, C_/32, E_), t32x8, 0, stream>>>(e_w1, w1t, C_, H_, C_, (size_t)H_ * C_);
  // w2 -> fp8 x256, blocked [64 chunks][c][64] with (c>>2) seg swizzle
  transpose_w2_fp8<<<dim3(H_/32, C_/32, E_), t32x8, 0, stream>>>(e_w2, w2f8);

  ln1_kernel<<<M_, 256, 0, stream>>>(x, ln1_g, ln1_b, h);
  gemm128<0><<<dim3(M_/128, C3_/128), 256, 0, stream>>>(h, wq, qkv_b, C_, C3_,
      nullptr, nullptr, qkv);
  scan1_kernel<<<B_*NCH_, 256, 0, stream>>>(qkv, S);
  scan2_kernel<<<B_, 256, 0, stream>>>(S);
  scan3_kernel<<<B_*NCH_, 256, 0, stream>>>(qkv, S, Pb);
  attn_kernel<<<M_/4, 256, 0, stream>>>(qkv, Pb, attn_g, aout);
  // x1 = x + aout @ proj_w + proj_b
  gemm128<1><<<dim3(M_/128, C_/128), 256, 0, stream>>>(aout, wp, proj_b, C_, C_,
      x, x1, nullptr);
  ln2_gates_kernel<<<M_, 256, 0, stream>>>(x1, ln2_g, ln2_b, gat_w, gat_b, h2, gts);
  // fused MoE: producer waves (up+gelu+fp8) || consumer waves (down), 1 barrier/iter
  moe_fused<<<M_/64, 512, 0, stream>>>(h2, w1t, e_b1, w2f8, e_b2, gts, x1, out);
}